// Round 13
// baseline (6530.558 us; speedup 1.0000x reference)
//
#include <hip/hip_runtime.h>

#define BM 64
#define NTHREADS 512   // atom_pre / legacy
#define BM4 32
#define NT8 512        // fused12: 8 waves, 2 blocks/CU

typedef __attribute__((ext_vector_type(8))) short short8;
typedef __attribute__((ext_vector_type(4))) short short4v;
typedef __attribute__((ext_vector_type(4))) float f32x4;

__device__ __forceinline__ short f2bf(float f) {
  unsigned u = __builtin_bit_cast(unsigned, f);
  u += 0x7FFFu + ((u >> 16) & 1u);   // RNE
  return (short)(u >> 16);
}
__device__ __forceinline__ float bf2f(short s) {
  unsigned u = ((unsigned)(unsigned short)s) << 16;
  return __builtin_bit_cast(float, u);
}
__device__ __forceinline__ float elu_f(float v) {
  return v > 0.f ? v : (__expf(v) - 1.f);
}
// packed RNE f32x2 -> bf16x2
__device__ __forceinline__ unsigned cvt_pk_bf16(float lo, float hi) {
  unsigned r;
  asm("v_cvt_pk_bf16_f32 %0, %1, %2" : "=v"(r) : "v"(lo), "v"(hi));
  return r;
}

// ---- pack f32 [K][N] weight into 16x16x32 MFMA fragment order ----
__global__ __launch_bounds__(256) void pack_w(const float* __restrict__ src,
                                              short* __restrict__ dst,
                                              int K, int N, int rev) {
  int tile = blockIdx.x * 4 + (threadIdx.x >> 6);
  int lane = threadIdx.x & 63;
  int ktiles = K >> 5;
  int tot = (N >> 4) * ktiles;
  if (tile >= tot) return;
  int nt = tile / ktiles, kt = tile - nt * ktiles;
  int col = (nt << 4) + (lane & 15);
  int k0 = (kt << 5) + ((lane >> 4) << 3);
  short8 o;
#pragma unroll
  for (int j = 0; j < 8; ++j) {
    int kr = k0 + j;
    if (rev) kr = ((3 - (kr >> 8)) << 8) | (kr & 255);
    o[j] = f2bf(src[(size_t)kr * N + col]);
  }
  *(short8*)(dst + (size_t)tile * 512 + lane * 8) = o;
}

__device__ __forceinline__ short8 ldg_bfrag(const short* W, int ktiles, int ct,
                                            int kt, int lane) {
  return *(const short8*)(W + ((size_t)(ct * ktiles + kt) << 9) + (lane << 3));
}

// swizzled LDS byte offset for activation tiles: stride 1024 B/row
__device__ __forceinline__ int swz(int row, int boff) {
  return row * 1024 + (boff ^ ((row & 7) << 4) ^ (((row >> 3) & 1) << 7));
}
// activation fragment read (MFMA B-operand): lane holds row m = mt*16+(lane&15),
// k = kt*32 + (lane>>4)*8 + j
__device__ __forceinline__ short8 lds_act(const char* base, int mt, int kt, int lane) {
  int row = mt * 16 + (lane & 15);
  int boff = (kt << 6) + ((lane >> 4) << 4);
  return *(const short8*)(base + swz(row, boff));
}

// ================= atom precompute (unchanged) =================
__device__ __forceinline__ short8 lds_afrag64(const char* base, int stride, int rt,
                                              int kt, int lane) {
  int row = rt * 16 + (lane & 15);
  int boff = (kt << 6) + ((lane >> 4) << 4);
  return *(const short8*)(base + row * stride + (boff ^ ((row & 7) << 4)));
}

__global__ __launch_bounds__(NTHREADS) void atom_pre(const float* __restrict__ h,
                                                     const short* __restrict__ W0f,
                                                     short* __restrict__ p,
                                                     int n_atoms) {
  __shared__ char sh[BM * 512];
  const int tid = threadIdx.x, lane = tid & 63, wv = tid >> 6;
  const int r0 = blockIdx.x * BM;
  for (int i = tid; i < BM * 32; i += NTHREADS) {
    int row = i >> 5, c0 = (i & 31) << 3;
    int ga = r0 + row;
    short8 o;
    if (ga < n_atoms) {
      const float4* s4 = (const float4*)(h + (size_t)ga * 256 + c0);
      float4 v0 = s4[0], v1 = s4[1];
      o[0] = f2bf(v0.x); o[1] = f2bf(v0.y); o[2] = f2bf(v0.z); o[3] = f2bf(v0.w);
      o[4] = f2bf(v1.x); o[5] = f2bf(v1.y); o[6] = f2bf(v1.z); o[7] = f2bf(v1.w);
    } else {
#pragma unroll
      for (int e = 0; e < 8; ++e) o[e] = 0;
    }
    *(short8*)(sh + row * 512 + ((c0 * 2) ^ ((row & 7) << 4))) = o;
  }
  __syncthreads();
#pragma unroll 1
  for (int s = 0; s < 4; ++s) {
    f32x4 acc[4][4];
    const f32x4 z = {0.f, 0.f, 0.f, 0.f};
#pragma unroll
    for (int rt = 0; rt < 4; ++rt)
#pragma unroll
      for (int cf = 0; cf < 4; ++cf) acc[rt][cf] = z;
    for (int kt = 0; kt < 8; ++kt) {
      short8 a[4], b[4];
#pragma unroll
      for (int rt = 0; rt < 4; ++rt) a[rt] = lds_afrag64(sh, 512, rt, kt, lane);
#pragma unroll
      for (int cf = 0; cf < 4; ++cf)
        b[cf] = ldg_bfrag(W0f, 32, (wv << 2) + cf, (s << 3) + kt, lane);
#pragma unroll
      for (int rt = 0; rt < 4; ++rt)
#pragma unroll
        for (int cf = 0; cf < 4; ++cf)
          acc[rt][cf] = __builtin_amdgcn_mfma_f32_16x16x32_bf16(a[rt], b[cf], acc[rt][cf], 0, 0, 0);
    }
#pragma unroll
    for (int rt = 0; rt < 4; ++rt)
#pragma unroll
      for (int cf = 0; cf < 4; ++cf) {
        int col = (wv << 6) + (cf << 4) + (lane & 15);
#pragma unroll
        for (int i = 0; i < 4; ++i) {
          int row = rt * 16 + ((lane >> 4) << 2) + i;
          int ga = r0 + row;
          if (ga < n_atoms) p[((size_t)ga * 4 + s) * 512 + col] = f2bf(acc[rt][cf][i]);
        }
      }
  }
}

struct P2 {
  const int* idxs;
  const short* p;
  const short *W1, *W2, *W3, *Wt0, *Wt1, *Wc0;
  const float *bs0, *bs1, *bs2, *bs3, *bt0, *bt1, *bt2, *bc0, *bc1;
  const float *Wt2, *Wc1;
  float* out;
  int n_tors;
};

// ================= fused12: fused11 + cross-barrier weight prefetch ============
// Transposed compute Y^T = W^T . X^T. Weight packed frag = A-operand; activation
// LDS read = B-operand. D: lane holds m = mt*16+(lane&15), n0..n0+3 consecutive.

struct WPre { short8 w[4]; };
__device__ __forceinline__ WPre pre_w4(const short* __restrict__ W, int wv, int lane) {
  WPre r;
#pragma unroll
  for (int nf = 0; nf < 4; ++nf) r.w[nf] = ldg_bfrag(W, 16, (wv << 2) + nf, 0, lane);
  return r;
}

__device__ __forceinline__ void bias_init(const float* __restrict__ bias,
                                          f32x4 (&acc)[2][4], int wv, int lane) {
#pragma unroll
  for (int nf = 0; nf < 4; ++nf) {
    const float4 bv = *(const float4*)(bias + (wv << 6) + (nf << 4) + ((lane >> 4) << 2));
    f32x4 v = {bv.x, bv.y, bv.z, bv.w};
    acc[0][nf] = v;
    acc[1][nf] = v;
  }
}

// dual-chain MFMA (shared weight-A), first-kt weights prefetched
__device__ __forceinline__ void mfma_dual12(const char* sA, const char* sB,
                                            const short* __restrict__ W,
                                            const float* __restrict__ bias,
                                            const WPre& pre,
                                            f32x4 (&aF)[2][4], f32x4 (&aR)[2][4],
                                            int wv, int lane) {
  bias_init(bias, aF, wv, lane);
  bias_init(bias, aR, wv, lane);
  short8 wc[4];
#pragma unroll
  for (int nf = 0; nf < 4; ++nf) wc[nf] = pre.w[nf];
#pragma unroll 4
  for (int kt = 0; kt < 16; ++kt) {
    short8 wn[4];
    if (kt < 15)
#pragma unroll
      for (int nf = 0; nf < 4; ++nf) wn[nf] = ldg_bfrag(W, 16, (wv << 2) + nf, kt + 1, lane);
    short8 bf_[2], br_[2];
#pragma unroll
    for (int mt = 0; mt < 2; ++mt) {
      bf_[mt] = lds_act(sA, mt, kt, lane);
      br_[mt] = lds_act(sB, mt, kt, lane);
    }
    __builtin_amdgcn_s_setprio(1);
#pragma unroll
    for (int mt = 0; mt < 2; ++mt)
#pragma unroll
      for (int nf = 0; nf < 4; ++nf) {
        aF[mt][nf] = __builtin_amdgcn_mfma_f32_16x16x32_bf16(wc[nf], bf_[mt], aF[mt][nf], 0, 0, 0);
        aR[mt][nf] = __builtin_amdgcn_mfma_f32_16x16x32_bf16(wc[nf], br_[mt], aR[mt][nf], 0, 0, 0);
      }
    __builtin_amdgcn_s_setprio(0);
#pragma unroll
    for (int nf = 0; nf < 4; ++nf) wc[nf] = wn[nf];
  }
}

// dual-weight MFMA: one activation stream (sym), two weight streams, prefetched
__device__ __forceinline__ void mfma_dualW12(const char* sA,
                                             const short* __restrict__ Wa,
                                             const short* __restrict__ Wb,
                                             const float* __restrict__ ba,
                                             const float* __restrict__ bb,
                                             const WPre& preA, const WPre& preB,
                                             f32x4 (&aA)[2][4], f32x4 (&aB)[2][4],
                                             int wv, int lane) {
  bias_init(ba, aA, wv, lane);
  bias_init(bb, aB, wv, lane);
  short8 wa[4], wb[4];
#pragma unroll
  for (int nf = 0; nf < 4; ++nf) { wa[nf] = preA.w[nf]; wb[nf] = preB.w[nf]; }
#pragma unroll 4
  for (int kt = 0; kt < 16; ++kt) {
    short8 na[4], nb[4];
    if (kt < 15)
#pragma unroll
      for (int nf = 0; nf < 4; ++nf) {
        na[nf] = ldg_bfrag(Wa, 16, (wv << 2) + nf, kt + 1, lane);
        nb[nf] = ldg_bfrag(Wb, 16, (wv << 2) + nf, kt + 1, lane);
      }
    short8 b[2];
#pragma unroll
    for (int mt = 0; mt < 2; ++mt) b[mt] = lds_act(sA, mt, kt, lane);
    __builtin_amdgcn_s_setprio(1);
#pragma unroll
    for (int mt = 0; mt < 2; ++mt)
#pragma unroll
      for (int nf = 0; nf < 4; ++nf) {
        aA[mt][nf] = __builtin_amdgcn_mfma_f32_16x16x32_bf16(wa[nf], b[mt], aA[mt][nf], 0, 0, 0);
        aB[mt][nf] = __builtin_amdgcn_mfma_f32_16x16x32_bf16(wb[nf], b[mt], aB[mt][nf], 0, 0, 0);
      }
    __builtin_amdgcn_s_setprio(0);
#pragma unroll
    for (int nf = 0; nf < 4; ++nf) { wa[nf] = na[nf]; wb[nf] = nb[nf]; }
  }
}

// single-chain MFMA, prefetched
__device__ __forceinline__ void mfma_single12(const char* src,
                                              const short* __restrict__ W,
                                              const float* __restrict__ bias,
                                              const WPre& pre,
                                              f32x4 (&acc)[2][4], int wv, int lane) {
  bias_init(bias, acc, wv, lane);
  short8 wc[4];
#pragma unroll
  for (int nf = 0; nf < 4; ++nf) wc[nf] = pre.w[nf];
#pragma unroll 4
  for (int kt = 0; kt < 16; ++kt) {
    short8 wn[4];
    if (kt < 15)
#pragma unroll
      for (int nf = 0; nf < 4; ++nf) wn[nf] = ldg_bfrag(W, 16, (wv << 2) + nf, kt + 1, lane);
    short8 b[2];
#pragma unroll
    for (int mt = 0; mt < 2; ++mt) b[mt] = lds_act(src, mt, kt, lane);
    __builtin_amdgcn_s_setprio(1);
#pragma unroll
    for (int mt = 0; mt < 2; ++mt)
#pragma unroll
      for (int nf = 0; nf < 4; ++nf)
        acc[mt][nf] = __builtin_amdgcn_mfma_f32_16x16x32_bf16(wc[nf], b[mt], acc[mt][nf], 0, 0, 0);
    __builtin_amdgcn_s_setprio(0);
#pragma unroll
    for (int nf = 0; nf < 4; ++nf) wc[nf] = wn[nf];
  }
}

// dual-chain epilogue: in-place residual update (isLast: write sym=f+r to sA only)
__device__ __forceinline__ void epi_dual12(char* sA, char* sB,
                                           const f32x4 (&accF)[2][4],
                                           const f32x4 (&accR)[2][4],
                                           int wv, int lane, bool isLast) {
#pragma unroll
  for (int mt = 0; mt < 2; ++mt)
#pragma unroll
    for (int nf = 0; nf < 4; ++nf) {
      int m = mt * 16 + (lane & 15);
      int nb = ((wv << 6) + (nf << 4) + ((lane >> 4) << 2)) << 1;
      int off = swz(m, nb);
      short4v rf = *(short4v*)(sA + off);
      short4v rr = *(short4v*)(sB + off);
      float vf[4], vr[4];
#pragma unroll
      for (int i = 0; i < 4; ++i) {
        vf[i] = bf2f(rf[i]) + elu_f(accF[mt][nf][i]);
        vr[i] = bf2f(rr[i]) + elu_f(accR[mt][nf][i]);
      }
      if (isLast) {
        uint2 o;
        o.x = cvt_pk_bf16(vf[0] + vr[0], vf[1] + vr[1]);
        o.y = cvt_pk_bf16(vf[2] + vr[2], vf[3] + vr[3]);
        *(uint2*)(sA + off) = o;
      } else {
        uint2 of, orv;
        of.x = cvt_pk_bf16(vf[0], vf[1]);
        of.y = cvt_pk_bf16(vf[2], vf[3]);
        orv.x = cvt_pk_bf16(vr[0], vr[1]);
        orv.y = cvt_pk_bf16(vr[2], vr[3]);
        *(uint2*)(sA + off) = of;
        *(uint2*)(sB + off) = orv;
      }
    }
}

__global__ __launch_bounds__(NT8, 4) void fused12(P2 p) {
  __shared__ char sA[BM4 * 1024];      // 32 KB, row-major [m][n] + XOR swizzle
  __shared__ char sB[BM4 * 1024];      // 32 KB
  __shared__ int sIdx[BM4 * 4];
  __shared__ float sSmall[BM4 * 12];
  const int tid = threadIdx.x;
  const int lane = tid & 63;
  const int wv = tid >> 6;             // 0..7 ; wave owns out-features wv*64..wv*64+63
  const int r0 = blockIdx.x * BM4;

  if (tid < BM4 * 4) {
    int grow = r0 + (tid >> 2);
    sIdx[tid] = (grow < p.n_tors) ? p.idxs[(size_t)grow * 4 + (tid & 3)] : 0;
  }
  __syncthreads();

  // ---- G: layer0 via gathered per-atom partials -> sA (fwd), sB (rev) ----
#pragma unroll 1
  for (int i = tid; i < BM4 * 64; i += NT8) {
    int row = i >> 6, c0 = (i & 63) << 3;
    float sf[8], sr[8];
#pragma unroll
    for (int e = 0; e < 8; ++e) { sf[e] = p.bs0[c0 + e]; sr[e] = sf[e]; }
#pragma unroll
    for (int j = 0; j < 4; ++j) {
      int a = sIdx[row * 4 + j];
      short8 vf = *(const short8*)(p.p + ((size_t)a * 4 + j) * 512 + c0);
      short8 vr = *(const short8*)(p.p + ((size_t)a * 4 + (3 - j)) * 512 + c0);
#pragma unroll
      for (int e = 0; e < 8; ++e) { sf[e] += bf2f(vf[e]); sr[e] += bf2f(vr[e]); }
    }
    uint4 of, orv;
    of.x = cvt_pk_bf16(elu_f(sf[0]), elu_f(sf[1]));
    of.y = cvt_pk_bf16(elu_f(sf[2]), elu_f(sf[3]));
    of.z = cvt_pk_bf16(elu_f(sf[4]), elu_f(sf[5]));
    of.w = cvt_pk_bf16(elu_f(sf[6]), elu_f(sf[7]));
    orv.x = cvt_pk_bf16(elu_f(sr[0]), elu_f(sr[1]));
    orv.y = cvt_pk_bf16(elu_f(sr[2]), elu_f(sr[3]));
    orv.z = cvt_pk_bf16(elu_f(sr[4]), elu_f(sr[5]));
    orv.w = cvt_pk_bf16(elu_f(sr[6]), elu_f(sr[7]));
    int off = swz(row, c0 * 2);
    *(uint4*)(sA + off) = of;
    *(uint4*)(sB + off) = orv;
  }
  WPre pw = pre_w4(p.W1, wv, lane);    // prefetch L1 kt=0 under G tail
  __syncthreads();

  f32x4 accF[2][4], accR[2][4];

  // ---- L1 ----
  mfma_dual12(sA, sB, p.W1, p.bs1, pw, accF, accR, wv, lane);
  __syncthreads();
  pw = pre_w4(p.W2, wv, lane);         // prefetch L2 under epilogue
  epi_dual12(sA, sB, accF, accR, wv, lane, false);
  __syncthreads();

  // ---- L2 ----
  mfma_dual12(sA, sB, p.W2, p.bs2, pw, accF, accR, wv, lane);
  __syncthreads();
  pw = pre_w4(p.W3, wv, lane);
  epi_dual12(sA, sB, accF, accR, wv, lane, false);
  __syncthreads();

  // ---- L3 (epilogue writes sym -> sA) ----
  mfma_dual12(sA, sB, p.W3, p.bs3, pw, accF, accR, wv, lane);
  __syncthreads();
  WPre pa = pre_w4(p.Wt0, wv, lane);
  WPre pb = pre_w4(p.Wc0, wv, lane);
  epi_dual12(sA, sB, accF, accR, wv, lane, true);
  __syncthreads();

  // ---- heads: t0 (Wt0) and c (Wc0) from sym (sA) ----
  mfma_dualW12(sA, p.Wt0, p.Wc0, p.bt0, p.bc0, pa, pb, accF, accR, wv, lane);
  __syncthreads();
  pw = pre_w4(p.Wt1, wv, lane);
#pragma unroll
  for (int mt = 0; mt < 2; ++mt)
#pragma unroll
    for (int nf = 0; nf < 4; ++nf) {
      int m = mt * 16 + (lane & 15);
      int nb = ((wv << 6) + (nf << 4) + ((lane >> 4) << 2)) << 1;
      int off = swz(m, nb);
      short4v sres = *(short4v*)(sA + off);
      float t0v[4], ccv[4];
#pragma unroll
      for (int i = 0; i < 4; ++i) {
        float s = bf2f(sres[i]);
        t0v[i] = s + elu_f(accF[mt][nf][i]);
        ccv[i] = s + elu_f(accR[mt][nf][i]);
      }
      uint2 t0, cc;
      t0.x = cvt_pk_bf16(t0v[0], t0v[1]);
      t0.y = cvt_pk_bf16(t0v[2], t0v[3]);
      cc.x = cvt_pk_bf16(ccv[0], ccv[1]);
      cc.y = cvt_pk_bf16(ccv[2], ccv[3]);
      *(uint2*)(sB + off) = t0;
      *(uint2*)(sA + off) = cc;
    }
  __syncthreads();

  // ---- t1 = t0 + elu(t0@Wt1+bt1), in-place in sB ----
  mfma_single12(sB, p.Wt1, p.bt1, pw, accF, wv, lane);
  __syncthreads();
#pragma unroll
  for (int mt = 0; mt < 2; ++mt)
#pragma unroll
    for (int nf = 0; nf < 4; ++nf) {
      int m = mt * 16 + (lane & 15);
      int nb = ((wv << 6) + (nf << 4) + ((lane >> 4) << 2)) << 1;
      int off = swz(m, nb);
      short4v rt_ = *(short4v*)(sB + off);
      float v[4];
#pragma unroll
      for (int i = 0; i < 4; ++i)
        v[i] = bf2f(rt_[i]) + elu_f(accF[mt][nf][i]);
      uint2 o;
      o.x = cvt_pk_bf16(v[0], v[1]);
      o.y = cvt_pk_bf16(v[2], v[3]);
      *(uint2*)(sB + off) = o;
    }
  __syncthreads();

  // ---- proj: coeffs from t1 (sB), score from c (sA) ----
  if (tid < BM4 * 12) {
    int row = tid / 12, jj = tid - row * 12;
    int j = (jj < 6) ? jj : jj - 6;
    const char* src = (jj < 6) ? sB : sA;
    const float* W = (jj < 6) ? p.Wt2 : p.Wc1;
    float acc = (jj < 6) ? p.bt2[j] : p.bc1[j];
#pragma unroll 1
    for (int c0 = 0; c0 < 512; c0 += 8) {
      short8 v = *(const short8*)(src + swz(row, c0 * 2));
#pragma unroll
      for (int e = 0; e < 8; ++e) acc += bf2f(v[e]) * W[(c0 + e) * 6 + j];
    }
    sSmall[row * 12 + jj] = acc;
  }
  __syncthreads();
  if (tid < BM4 * 6) {
    int row = tid / 6, j = tid - row * 6;
    int grow = r0 + row;
    if (grow < p.n_tors) {
      float score = sSmall[row * 12 + 6 + j];
      float coeff = sSmall[row * 12 + j];
      p.out[(size_t)grow * 6 + j] = score;
      p.out[(size_t)p.n_tors * 6 + (size_t)grow * 6 + j] =
          coeff * 0.001f * (1.0f / (1.0f + __expf(-score)));
    }
  }
}

// ================= LEGACY PATH (fallback if ws too small) =================

struct Params {
  const float* h;
  const int* idxs;
  const short *W0f, *W0r, *W1, *W2, *W3, *Wt0, *Wt1, *Wc0;
  const float *bs0, *bs1, *bs2, *bs3, *bt0, *bt1, *bt2, *bc0, *bc1;
  const float *Wt2, *Wc1;
  float* out;
  int n_tors;
};

__device__ __forceinline__ void layer_dual(char* hf, char* hr,
                                           const short* __restrict__ W,
                                           const float* __restrict__ bias,
                                           int wv, int lane) {
  f32x4 accf[4][4], accr[4][4];
  const f32x4 z = {0.f, 0.f, 0.f, 0.f};
#pragma unroll
  for (int rt = 0; rt < 4; ++rt)
#pragma unroll
    for (int cf = 0; cf < 4; ++cf) { accf[rt][cf] = z; accr[rt][cf] = z; }
  for (int kt = 0; kt < 16; ++kt) {
    short8 af[4], ar[4], b[4];
#pragma unroll
    for (int rt = 0; rt < 4; ++rt) {
      af[rt] = lds_afrag64(hf, 1024, rt, kt, lane);
      ar[rt] = lds_afrag64(hr, 1024, rt, kt, lane);
    }
#pragma unroll
    for (int cf = 0; cf < 4; ++cf) b[cf] = ldg_bfrag(W, 16, (wv << 2) + cf, kt, lane);
#pragma unroll
    for (int rt = 0; rt < 4; ++rt)
#pragma unroll
      for (int cf = 0; cf < 4; ++cf) {
        accf[rt][cf] = __builtin_amdgcn_mfma_f32_16x16x32_bf16(af[rt], b[cf], accf[rt][cf], 0, 0, 0);
        accr[rt][cf] = __builtin_amdgcn_mfma_f32_16x16x32_bf16(ar[rt], b[cf], accr[rt][cf], 0, 0, 0);
      }
  }
  float bcol[4];
#pragma unroll
  for (int cf = 0; cf < 4; ++cf) bcol[cf] = bias[(wv << 6) + (cf << 4) + (lane & 15)];
  __syncthreads();
#pragma unroll
  for (int rt = 0; rt < 4; ++rt)
#pragma unroll
    for (int cf = 0; cf < 4; ++cf) {
      int col = (wv << 6) + (cf << 4) + (lane & 15);
#pragma unroll
      for (int i = 0; i < 4; ++i) {
        int row = rt * 16 + ((lane >> 4) << 2) + i;
        size_t off = (size_t)row * 1024 + ((col * 2) ^ ((row & 7) << 4));
        short* pf = (short*)(hf + off);
        short* pr = (short*)(hr + off);
        *pf = f2bf(bf2f(*pf) + elu_f(accf[rt][cf][i] + bcol[cf]));
        *pr = f2bf(bf2f(*pr) + elu_f(accr[rt][cf][i] + bcol[cf]));
      }
    }
  __syncthreads();
}

__device__ __forceinline__ void layer_single(const char* in,
                                             const short* __restrict__ W,
                                             const float* __restrict__ bias,
                                             const char* res, char* out,
                                             int wv, int lane) {
  f32x4 acc[4][4];
  const f32x4 z = {0.f, 0.f, 0.f, 0.f};
#pragma unroll
  for (int rt = 0; rt < 4; ++rt)
#pragma unroll
    for (int cf = 0; cf < 4; ++cf) acc[rt][cf] = z;
  for (int kt = 0; kt < 16; ++kt) {
    short8 a[4], b[4];
#pragma unroll
    for (int rt = 0; rt < 4; ++rt) a[rt] = lds_afrag64(in, 1024, rt, kt, lane);
#pragma unroll
    for (int cf = 0; cf < 4; ++cf) b[cf] = ldg_bfrag(W, 16, (wv << 2) + cf, kt, lane);
#pragma unroll
    for (int rt = 0; rt < 4; ++rt)
#pragma unroll
      for (int cf = 0; cf < 4; ++cf)
        acc[rt][cf] = __builtin_amdgcn_mfma_f32_16x16x32_bf16(a[rt], b[cf], acc[rt][cf], 0, 0, 0);
  }
  float bcol[4];
#pragma unroll
  for (int cf = 0; cf < 4; ++cf) bcol[cf] = bias[(wv << 6) + (cf << 4) + (lane & 15)];
  __syncthreads();
#pragma unroll
  for (int rt = 0; rt < 4; ++rt)
#pragma unroll
    for (int cf = 0; cf < 4; ++cf) {
      int col = (wv << 6) + (cf << 4) + (lane & 15);
#pragma unroll
      for (int i = 0; i < 4; ++i) {
        int row = rt * 16 + ((lane >> 4) << 2) + i;
        size_t off = (size_t)row * 1024 + ((col * 2) ^ ((row & 7) << 4));
        float v = elu_f(acc[rt][cf][i] + bcol[cf]) + bf2f(*(const short*)(res + off));
        *(short*)(out + off) = f2bf(v);
      }
    }
  __syncthreads();
}

__global__ __launch_bounds__(NTHREADS) void fused(Params p) {
  __shared__ char smem[BM * 2048];
  __shared__ float sSmall[BM * 12];
  char* sA = smem;
  char* sB = smem + BM * 1024;
  const int tid = threadIdx.x;
  const int lane = tid & 63;
  const int wv = tid >> 6;
  const int r0 = blockIdx.x * BM;

  for (int c = tid; c < BM * 128; c += NTHREADS) {
    int row = c >> 7;
    int col0 = (c & 127) << 3;
    int grow = r0 + row;
    short8 o;
    if (grow < p.n_tors) {
      int f = col0 >> 8;
      int cin = col0 & 255;
      int a = p.idxs[(size_t)grow * 4 + f];
      const float4* s4 = (const float4*)(p.h + (size_t)a * 256 + cin);
      float4 v0 = s4[0], v1 = s4[1];
      o[0] = f2bf(v0.x); o[1] = f2bf(v0.y); o[2] = f2bf(v0.z); o[3] = f2bf(v0.w);
      o[4] = f2bf(v1.x); o[5] = f2bf(v1.y); o[6] = f2bf(v1.z); o[7] = f2bf(v1.w);
    } else {
#pragma unroll
      for (int e = 0; e < 8; ++e) o[e] = 0;
    }
    *(short8*)(smem + (size_t)row * 2048 + ((col0 * 2) ^ ((row & 7) << 4))) = o;
  }
  __syncthreads();

  {
    f32x4 accf[4][4], accr[4][4];
    const f32x4 z = {0.f, 0.f, 0.f, 0.f};
#pragma unroll
    for (int rt = 0; rt < 4; ++rt)
#pragma unroll
      for (int cf = 0; cf < 4; ++cf) { accf[rt][cf] = z; accr[rt][cf] = z; }
    for (int kt = 0; kt < 32; ++kt) {
      short8 a[4], bfw[4], brw[4];
#pragma unroll
      for (int rt = 0; rt < 4; ++rt) a[rt] = lds_afrag64(smem, 2048, rt, kt, lane);
#pragma unroll
      for (int cf = 0; cf < 4; ++cf) {
        bfw[cf] = ldg_bfrag(p.W0f, 32, (wv << 2) + cf, kt, lane);
        brw[cf] = ldg_bfrag(p.W0r, 32, (wv << 2) + cf, kt, lane);
      }
#pragma unroll
      for (int rt = 0; rt < 4; ++rt)
#pragma unroll
        for (int cf = 0; cf < 4; ++cf) {
          accf[rt][cf] = __builtin_amdgcn_mfma_f32_16x16x32_bf16(a[rt], bfw[cf], accf[rt][cf], 0, 0, 0);
          accr[rt][cf] = __builtin_amdgcn_mfma_f32_16x16x32_bf16(a[rt], brw[cf], accr[rt][cf], 0, 0, 0);
        }
    }
    float bcol[4];
#pragma unroll
    for (int cf = 0; cf < 4; ++cf) bcol[cf] = p.bs0[(wv << 6) + (cf << 4) + (lane & 15)];
    __syncthreads();
#pragma unroll
    for (int rt = 0; rt < 4; ++rt)
#pragma unroll
      for (int cf = 0; cf < 4; ++cf) {
        int col = (wv << 6) + (cf << 4) + (lane & 15);
#pragma unroll
        for (int i = 0; i < 4; ++i) {
          int row = rt * 16 + ((lane >> 4) << 2) + i;
          size_t off = (size_t)row * 1024 + ((col * 2) ^ ((row & 7) << 4));
          *(short*)(sA + off) = f2bf(elu_f(accf[rt][cf][i] + bcol[cf]));
          *(short*)(sB + off) = f2bf(elu_f(accr[rt][cf][i] + bcol[cf]));
        }
      }
    __syncthreads();
  }

  layer_dual(sA, sB, p.W1, p.bs1, wv, lane);
  layer_dual(sA, sB, p.W2, p.bs2, wv, lane);
  layer_dual(sA, sB, p.W3, p.bs3, wv, lane);

  for (int c = tid; c < BM * 64; c += NTHREADS) {
    int row = c >> 6;
    int col0 = (c & 63) << 3;
    size_t off = (size_t)row * 1024 + ((col0 * 2) ^ ((row & 7) << 4));
    short8 xa = *(short8*)(sA + off);
    short8 xb = *(short8*)(sB + off);
    short8 o;
#pragma unroll
    for (int e = 0; e < 8; ++e) o[e] = f2bf(bf2f(xa[e]) + bf2f(xb[e]));
    *(short8*)(sA + off) = o;
  }
  __syncthreads();

  layer_single(sA, p.Wt0, p.bt0, sA, sB, wv, lane);
  layer_single(sB, p.Wt1, p.bt1, sB, sB, wv, lane);
  layer_single(sA, p.Wc0, p.bc0, sA, sA, wv, lane);

  for (int idx = tid; idx < BM * 12; idx += NTHREADS) {
    int row = idx / 12, jj = idx - row * 12;
    int j = (jj < 6) ? jj : jj - 6;
    const char* src = (jj < 6) ? sB : sA;
    const float* W = (jj < 6) ? p.Wt2 : p.Wc1;
    float acc = (jj < 6) ? p.bt2[j] : p.bc1[j];
    for (int c0 = 0; c0 < 512; c0 += 8) {
      short8 v = *(const short8*)(src + (size_t)row * 1024 + ((c0 * 2) ^ ((row & 7) << 4)));
#pragma unroll
      for (int e = 0; e < 8; ++e) acc += bf2f(v[e]) * W[(c0 + e) * 6 + j];
    }
    sSmall[row * 12 + jj] = acc;
  }
  __syncthreads();
  for (int idx = tid; idx < BM * 6; idx += NTHREADS) {
    int row = idx / 6, j = idx - row * 6;
    int grow = r0 + row;
    if (grow < p.n_tors) {
      float score = sSmall[row * 12 + 6 + j];
      float coeff = sSmall[row * 12 + j];
      p.out[(size_t)grow * 6 + j] = score;
      p.out[(size_t)p.n_tors * 6 + (size_t)grow * 6 + j] =
          coeff * 0.001f * (1.0f / (1.0f + __expf(-score)));
    }
  }
}

// ================= LAUNCH =================

extern "C" void kernel_launch(void* const* d_in, const int* in_sizes, int n_in,
                              void* d_out, int out_size, void* d_ws, size_t ws_size,
                              hipStream_t stream) {
  const float* h   = (const float*)d_in[0];
  const int* idxs  = (const int*)d_in[1];
  const float* Ws0 = (const float*)d_in[2];
  const float* bs0 = (const float*)d_in[3];
  const float* Ws1 = (const float*)d_in[4];
  const float* bs1 = (const float*)d_in[5];
  const float* Ws2 = (const float*)d_in[6];
  const float* bs2 = (const float*)d_in[7];
  const float* Ws3 = (const float*)d_in[8];
  const float* bs3 = (const float*)d_in[9];
  const float* Wt0 = (const float*)d_in[10];
  const float* bt0 = (const float*)d_in[11];
  const float* Wt1 = (const float*)d_in[12];
  const float* bt1 = (const float*)d_in[13];
  const float* Wt2 = (const float*)d_in[14];
  const float* bt2 = (const float*)d_in[15];
  const float* Wc0 = (const float*)d_in[16];
  const float* bc0 = (const float*)d_in[17];
  const float* Wc1 = (const float*)d_in[18];
  const float* bc1 = (const float*)d_in[19];
  int n_tors = in_sizes[1] / 4;
  int n_atoms = in_sizes[0] / 256;

  auto pk = [&](const float* s, short* dmem, int K, int N, int rev) {
    int tiles = (N >> 4) * (K >> 5);
    pack_w<<<dim3((tiles + 3) / 4), dim3(256), 0, stream>>>(s, dmem, K, N, rev);
  };

  size_t pElems = (size_t)n_atoms * 4 * 512;
  size_t needNew = (pElems + 524288 + 6 * 262144) * sizeof(short);

  if (ws_size >= needNew) {
    short* ws = (short*)d_ws;
    short* pT  = ws;
    short* W0f = ws + pElems;
    short* W1  = W0f + 524288;
    short* W2  = W1 + 262144;
    short* W3  = W2 + 262144;
    short* Wt0c = W3 + 262144;
    short* Wt1c = Wt0c + 262144;
    short* Wc0c = Wt1c + 262144;

    pk(Ws0, W0f, 1024, 512, 0);
    pk(Ws1, W1, 512, 512, 0);
    pk(Ws2, W2, 512, 512, 0);
    pk(Ws3, W3, 512, 512, 0);
    pk(Wt0, Wt0c, 512, 512, 0);
    pk(Wt1, Wt1c, 512, 512, 0);
    pk(Wc0, Wc0c, 512, 512, 0);

    atom_pre<<<dim3((n_atoms + BM - 1) / BM), dim3(NTHREADS), 0, stream>>>(h, W0f, pT, n_atoms);

    P2 p;
    p.idxs = idxs; p.p = pT;
    p.W1 = W1; p.W2 = W2; p.W3 = W3;
    p.Wt0 = Wt0c; p.Wt1 = Wt1c; p.Wc0 = Wc0c;
    p.bs0 = bs0; p.bs1 = bs1; p.bs2 = bs2; p.bs3 = bs3;
    p.bt0 = bt0; p.bt1 = bt1; p.bt2 = bt2; p.bc0 = bc0; p.bc1 = bc1;
    p.Wt2 = Wt2; p.Wc1 = Wc1;
    p.out = (float*)d_out; p.n_tors = n_tors;

    fused12<<<dim3((n_tors + BM4 - 1) / BM4), dim3(NT8), 0, stream>>>(p);
  } else {
    short* ws = (short*)d_ws;
    short* W0f = ws;
    short* W0r = ws + 524288;
    short* W1  = ws + 1048576;
    short* W2  = W1 + 262144;
    short* W3  = W2 + 262144;
    short* Wt0c = W3 + 262144;
    short* Wt1c = Wt0c + 262144;
    short* Wc0c = Wt1c + 262144;

    pk(Ws0, W0f, 1024, 512, 0);
    pk(Ws0, W0r, 1024, 512, 1);
    pk(Ws1, W1, 512, 512, 0);
    pk(Ws2, W2, 512, 512, 0);
    pk(Ws3, W3, 512, 512, 0);
    pk(Wt0, Wt0c, 512, 512, 0);
    pk(Wt1, Wt1c, 512, 512, 0);
    pk(Wc0, Wc0c, 512, 512, 0);

    Params p;
    p.h = h; p.idxs = idxs;
    p.W0f = W0f; p.W0r = W0r; p.W1 = W1; p.W2 = W2; p.W3 = W3;
    p.Wt0 = Wt0c; p.Wt1 = Wt1c; p.Wc0 = Wc0c;
    p.bs0 = bs0; p.bs1 = bs1; p.bs2 = bs2; p.bs3 = bs3;
    p.bt0 = bt0; p.bt1 = bt1; p.bt2 = bt2; p.bc0 = bc0; p.bc1 = bc1;
    p.Wt2 = Wt2; p.Wc1 = Wc1;
    p.out = (float*)d_out; p.n_tors = n_tors;

    fused<<<dim3((n_tors + BM - 1) / BM), dim3(NTHREADS), 0, stream>>>(p);
  }
}

// Round 14
// 2958.468 us; speedup vs baseline: 2.2074x; 2.2074x over previous
//
#include <hip/hip_runtime.h>

#define BM 64
#define NTHREADS 512   // atom_pre / legacy
#define BM4 32
#define NT8 512        // fused13: 8 waves, 2 blocks/CU

typedef __attribute__((ext_vector_type(8))) short short8;
typedef __attribute__((ext_vector_type(4))) short short4v;
typedef __attribute__((ext_vector_type(4))) float f32x4;

__device__ __forceinline__ short f2bf(float f) {
  unsigned u = __builtin_bit_cast(unsigned, f);
  u += 0x7FFFu + ((u >> 16) & 1u);   // RNE
  return (short)(u >> 16);
}
__device__ __forceinline__ float bf2f(short s) {
  unsigned u = ((unsigned)(unsigned short)s) << 16;
  return __builtin_bit_cast(float, u);
}
__device__ __forceinline__ float elu_f(float v) {
  return v > 0.f ? v : (__expf(v) - 1.f);
}
// packed RNE f32x2 -> bf16x2
__device__ __forceinline__ unsigned cvt_pk_bf16(float lo, float hi) {
  unsigned r;
  asm("v_cvt_pk_bf16_f32 %0, %1, %2" : "=v"(r) : "v"(lo), "v"(hi));
  return r;
}
// unpack uint2 of 4 bf16 -> 4 f32
__device__ __forceinline__ void unpk4(uint2 u, float (&v)[4]) {
  v[0] = bf2f((short)(u.x & 0xffff));
  v[1] = bf2f((short)(u.x >> 16));
  v[2] = bf2f((short)(u.y & 0xffff));
  v[3] = bf2f((short)(u.y >> 16));
}

// ---- pack f32 [K][N] weight into 16x16x32 MFMA fragment order ----
__global__ __launch_bounds__(256) void pack_w(const float* __restrict__ src,
                                              short* __restrict__ dst,
                                              int K, int N, int rev) {
  int tile = blockIdx.x * 4 + (threadIdx.x >> 6);
  int lane = threadIdx.x & 63;
  int ktiles = K >> 5;
  int tot = (N >> 4) * ktiles;
  if (tile >= tot) return;
  int nt = tile / ktiles, kt = tile - nt * ktiles;
  int col = (nt << 4) + (lane & 15);
  int k0 = (kt << 5) + ((lane >> 4) << 3);
  short8 o;
#pragma unroll
  for (int j = 0; j < 8; ++j) {
    int kr = k0 + j;
    if (rev) kr = ((3 - (kr >> 8)) << 8) | (kr & 255);
    o[j] = f2bf(src[(size_t)kr * N + col]);
  }
  *(short8*)(dst + (size_t)tile * 512 + lane * 8) = o;
}

__device__ __forceinline__ short8 ldg_bfrag(const short* W, int ktiles, int ct,
                                            int kt, int lane) {
  return *(const short8*)(W + ((size_t)(ct * ktiles + kt) << 9) + (lane << 3));
}

// swizzled LDS byte offset for activation tiles: stride 1024 B/row
__device__ __forceinline__ int swz(int row, int boff) {
  return row * 1024 + (boff ^ ((row & 7) << 4) ^ (((row >> 3) & 1) << 7));
}
// activation fragment read (MFMA B-operand): lane holds row m = mt*16+(lane&15),
// k = kt*32 + (lane>>4)*8 + j
__device__ __forceinline__ short8 lds_act(const char* base, int mt, int kt, int lane) {
  int row = mt * 16 + (lane & 15);
  int boff = (kt << 6) + ((lane >> 4) << 4);
  return *(const short8*)(base + swz(row, boff));
}

// ================= atom precompute (unchanged) =================
__device__ __forceinline__ short8 lds_afrag64(const char* base, int stride, int rt,
                                              int kt, int lane) {
  int row = rt * 16 + (lane & 15);
  int boff = (kt << 6) + ((lane >> 4) << 4);
  return *(const short8*)(base + row * stride + (boff ^ ((row & 7) << 4)));
}

__global__ __launch_bounds__(NTHREADS) void atom_pre(const float* __restrict__ h,
                                                     const short* __restrict__ W0f,
                                                     short* __restrict__ p,
                                                     int n_atoms) {
  __shared__ char sh[BM * 512];
  const int tid = threadIdx.x, lane = tid & 63, wv = tid >> 6;
  const int r0 = blockIdx.x * BM;
  for (int i = tid; i < BM * 32; i += NTHREADS) {
    int row = i >> 5, c0 = (i & 31) << 3;
    int ga = r0 + row;
    short8 o;
    if (ga < n_atoms) {
      const float4* s4 = (const float4*)(h + (size_t)ga * 256 + c0);
      float4 v0 = s4[0], v1 = s4[1];
      o[0] = f2bf(v0.x); o[1] = f2bf(v0.y); o[2] = f2bf(v0.z); o[3] = f2bf(v0.w);
      o[4] = f2bf(v1.x); o[5] = f2bf(v1.y); o[6] = f2bf(v1.z); o[7] = f2bf(v1.w);
    } else {
#pragma unroll
      for (int e = 0; e < 8; ++e) o[e] = 0;
    }
    *(short8*)(sh + row * 512 + ((c0 * 2) ^ ((row & 7) << 4))) = o;
  }
  __syncthreads();
#pragma unroll 1
  for (int s = 0; s < 4; ++s) {
    f32x4 acc[4][4];
    const f32x4 z = {0.f, 0.f, 0.f, 0.f};
#pragma unroll
    for (int rt = 0; rt < 4; ++rt)
#pragma unroll
      for (int cf = 0; cf < 4; ++cf) acc[rt][cf] = z;
    for (int kt = 0; kt < 8; ++kt) {
      short8 a[4], b[4];
#pragma unroll
      for (int rt = 0; rt < 4; ++rt) a[rt] = lds_afrag64(sh, 512, rt, kt, lane);
#pragma unroll
      for (int cf = 0; cf < 4; ++cf)
        b[cf] = ldg_bfrag(W0f, 32, (wv << 2) + cf, (s << 3) + kt, lane);
#pragma unroll
      for (int rt = 0; rt < 4; ++rt)
#pragma unroll
        for (int cf = 0; cf < 4; ++cf)
          acc[rt][cf] = __builtin_amdgcn_mfma_f32_16x16x32_bf16(a[rt], b[cf], acc[rt][cf], 0, 0, 0);
    }
#pragma unroll
    for (int rt = 0; rt < 4; ++rt)
#pragma unroll
      for (int cf = 0; cf < 4; ++cf) {
        int col = (wv << 6) + (cf << 4) + (lane & 15);
#pragma unroll
        for (int i = 0; i < 4; ++i) {
          int row = rt * 16 + ((lane >> 4) << 2) + i;
          int ga = r0 + row;
          if (ga < n_atoms) p[((size_t)ga * 4 + s) * 512 + col] = f2bf(acc[rt][cf][i]);
        }
      }
  }
}

struct P2 {
  const int* idxs;
  const short* p;
  const short *W1, *W2, *W3, *Wt0, *Wt1, *Wc0;
  const float *bs0, *bs1, *bs2, *bs3, *bt0, *bt1, *bt2, *bc0, *bc1;
  const float *Wt2, *Wc1;
  float* out;
  int n_tors;
};

// ================= fused13: fused11 + register-resident residuals ==============
// Transposed compute Y^T = W^T . X^T. Weight packed frag = A-operand; activation
// LDS read = B-operand. D: lane holds m = mt*16+(lane&15), n0..n0+3 consecutive.
// Epilogue residuals carried as packed bf16 uint2 in registers across phases
// (mapping (mt,nf,lane)->LDS slot is phase-invariant) -> no LDS residual reads.

__device__ __forceinline__ void bias_init(const float* __restrict__ bias,
                                          f32x4 (&acc)[2][4], int wv, int lane) {
#pragma unroll
  for (int nf = 0; nf < 4; ++nf) {
    const float4 bv = *(const float4*)(bias + (wv << 6) + (nf << 4) + ((lane >> 4) << 2));
    f32x4 v = {bv.x, bv.y, bv.z, bv.w};
    acc[0][nf] = v;
    acc[1][nf] = v;
  }
}

// dual-chain MFMA (shared weight-A): aF = bias + X_A@W, aR = bias + X_B@W
__device__ __forceinline__ void mfma_dual13(const char* sA, const char* sB,
                                            const short* __restrict__ W,
                                            const float* __restrict__ bias,
                                            f32x4 (&aF)[2][4], f32x4 (&aR)[2][4],
                                            int wv, int lane) {
  bias_init(bias, aF, wv, lane);
  bias_init(bias, aR, wv, lane);
#pragma unroll 4
  for (int kt = 0; kt < 16; ++kt) {
    short8 w[4];
#pragma unroll
    for (int nf = 0; nf < 4; ++nf) w[nf] = ldg_bfrag(W, 16, (wv << 2) + nf, kt, lane);
    short8 bf_[2], br_[2];
#pragma unroll
    for (int mt = 0; mt < 2; ++mt) {
      bf_[mt] = lds_act(sA, mt, kt, lane);
      br_[mt] = lds_act(sB, mt, kt, lane);
    }
    __builtin_amdgcn_s_setprio(1);
#pragma unroll
    for (int mt = 0; mt < 2; ++mt)
#pragma unroll
      for (int nf = 0; nf < 4; ++nf) {
        aF[mt][nf] = __builtin_amdgcn_mfma_f32_16x16x32_bf16(w[nf], bf_[mt], aF[mt][nf], 0, 0, 0);
        aR[mt][nf] = __builtin_amdgcn_mfma_f32_16x16x32_bf16(w[nf], br_[mt], aR[mt][nf], 0, 0, 0);
      }
    __builtin_amdgcn_s_setprio(0);
  }
}

// dual-weight MFMA: one activation stream (sym), two weight streams
__device__ __forceinline__ void mfma_dualW13(const char* sA,
                                             const short* __restrict__ Wa,
                                             const short* __restrict__ Wb,
                                             const float* __restrict__ ba,
                                             const float* __restrict__ bb,
                                             f32x4 (&aA)[2][4], f32x4 (&aB)[2][4],
                                             int wv, int lane) {
  bias_init(ba, aA, wv, lane);
  bias_init(bb, aB, wv, lane);
#pragma unroll 4
  for (int kt = 0; kt < 16; ++kt) {
    short8 wA[4], wB[4];
#pragma unroll
    for (int nf = 0; nf < 4; ++nf) {
      wA[nf] = ldg_bfrag(Wa, 16, (wv << 2) + nf, kt, lane);
      wB[nf] = ldg_bfrag(Wb, 16, (wv << 2) + nf, kt, lane);
    }
    short8 b[2];
#pragma unroll
    for (int mt = 0; mt < 2; ++mt) b[mt] = lds_act(sA, mt, kt, lane);
    __builtin_amdgcn_s_setprio(1);
#pragma unroll
    for (int mt = 0; mt < 2; ++mt)
#pragma unroll
      for (int nf = 0; nf < 4; ++nf) {
        aA[mt][nf] = __builtin_amdgcn_mfma_f32_16x16x32_bf16(wA[nf], b[mt], aA[mt][nf], 0, 0, 0);
        aB[mt][nf] = __builtin_amdgcn_mfma_f32_16x16x32_bf16(wB[nf], b[mt], aB[mt][nf], 0, 0, 0);
      }
    __builtin_amdgcn_s_setprio(0);
  }
}

// single-chain MFMA
__device__ __forceinline__ void mfma_single13(const char* src,
                                              const short* __restrict__ W,
                                              const float* __restrict__ bias,
                                              f32x4 (&acc)[2][4], int wv, int lane) {
  bias_init(bias, acc, wv, lane);
#pragma unroll 4
  for (int kt = 0; kt < 16; ++kt) {
    short8 w[4];
#pragma unroll
    for (int nf = 0; nf < 4; ++nf) w[nf] = ldg_bfrag(W, 16, (wv << 2) + nf, kt, lane);
    short8 b[2];
#pragma unroll
    for (int mt = 0; mt < 2; ++mt) b[mt] = lds_act(src, mt, kt, lane);
    __builtin_amdgcn_s_setprio(1);
#pragma unroll
    for (int mt = 0; mt < 2; ++mt)
#pragma unroll
      for (int nf = 0; nf < 4; ++nf)
        acc[mt][nf] = __builtin_amdgcn_mfma_f32_16x16x32_bf16(w[nf], b[mt], acc[mt][nf], 0, 0, 0);
    __builtin_amdgcn_s_setprio(0);
  }
}

__global__ __launch_bounds__(NT8, 4) void fused13(P2 p) {
  __shared__ char sA[BM4 * 1024];      // 32 KB, row-major [m][n] + XOR swizzle
  __shared__ char sB[BM4 * 1024];      // 32 KB
  __shared__ int sIdx[BM4 * 4];
  __shared__ float sSmall[BM4 * 12];
  const int tid = threadIdx.x;
  const int lane = tid & 63;
  const int wv = tid >> 6;             // 0..7 ; wave owns out-features wv*64..wv*64+63
  const int r0 = blockIdx.x * BM4;

  if (tid < BM4 * 4) {
    int grow = r0 + (tid >> 2);
    sIdx[tid] = (grow < p.n_tors) ? p.idxs[(size_t)grow * 4 + (tid & 3)] : 0;
  }
  __syncthreads();

  // ---- G: layer0 via gathered per-atom partials -> sA (fwd), sB (rev) ----
#pragma unroll 1
  for (int i = tid; i < BM4 * 64; i += NT8) {
    int row = i >> 6, c0 = (i & 63) << 3;
    float sf[8], sr[8];
#pragma unroll
    for (int e = 0; e < 8; ++e) { sf[e] = p.bs0[c0 + e]; sr[e] = sf[e]; }
#pragma unroll
    for (int j = 0; j < 4; ++j) {
      int a = sIdx[row * 4 + j];
      short8 vf = *(const short8*)(p.p + ((size_t)a * 4 + j) * 512 + c0);
      short8 vr = *(const short8*)(p.p + ((size_t)a * 4 + (3 - j)) * 512 + c0);
#pragma unroll
      for (int e = 0; e < 8; ++e) { sf[e] += bf2f(vf[e]); sr[e] += bf2f(vr[e]); }
    }
    uint4 of, orv;
    of.x = cvt_pk_bf16(elu_f(sf[0]), elu_f(sf[1]));
    of.y = cvt_pk_bf16(elu_f(sf[2]), elu_f(sf[3]));
    of.z = cvt_pk_bf16(elu_f(sf[4]), elu_f(sf[5]));
    of.w = cvt_pk_bf16(elu_f(sf[6]), elu_f(sf[7]));
    orv.x = cvt_pk_bf16(elu_f(sr[0]), elu_f(sr[1]));
    orv.y = cvt_pk_bf16(elu_f(sr[2]), elu_f(sr[3]));
    orv.z = cvt_pk_bf16(elu_f(sr[4]), elu_f(sr[5]));
    orv.w = cvt_pk_bf16(elu_f(sr[6]), elu_f(sr[7]));
    int off = swz(row, c0 * 2);
    *(uint4*)(sA + off) = of;
    *(uint4*)(sB + off) = orv;
  }
  __syncthreads();

  f32x4 accF[2][4], accR[2][4];
  uint2 resF[2][4], resR[2][4];        // packed bf16 residuals (phase-invariant slots)

  // ---- L1 (residual read from LDS once; results cached in regs) ----
  mfma_dual13(sA, sB, p.W1, p.bs1, accF, accR, wv, lane);
  __syncthreads();
#pragma unroll
  for (int mt = 0; mt < 2; ++mt)
#pragma unroll
    for (int nf = 0; nf < 4; ++nf) {
      int m = mt * 16 + (lane & 15);
      int nb = ((wv << 6) + (nf << 4) + ((lane >> 4) << 2)) << 1;
      int off = swz(m, nb);
      short4v rf = *(short4v*)(sA + off);
      short4v rr = *(short4v*)(sB + off);
      float vf[4], vr[4];
#pragma unroll
      for (int i = 0; i < 4; ++i) {
        vf[i] = bf2f(rf[i]) + elu_f(accF[mt][nf][i]);
        vr[i] = bf2f(rr[i]) + elu_f(accR[mt][nf][i]);
      }
      uint2 of, orv;
      of.x = cvt_pk_bf16(vf[0], vf[1]);
      of.y = cvt_pk_bf16(vf[2], vf[3]);
      orv.x = cvt_pk_bf16(vr[0], vr[1]);
      orv.y = cvt_pk_bf16(vr[2], vr[3]);
      *(uint2*)(sA + off) = of;
      *(uint2*)(sB + off) = orv;
      resF[mt][nf] = of;
      resR[mt][nf] = orv;
    }
  __syncthreads();

  // ---- L2 (residual from regs) ----
  mfma_dual13(sA, sB, p.W2, p.bs2, accF, accR, wv, lane);
  __syncthreads();
#pragma unroll
  for (int mt = 0; mt < 2; ++mt)
#pragma unroll
    for (int nf = 0; nf < 4; ++nf) {
      int m = mt * 16 + (lane & 15);
      int nb = ((wv << 6) + (nf << 4) + ((lane >> 4) << 2)) << 1;
      int off = swz(m, nb);
      float pf[4], pr[4];
      unpk4(resF[mt][nf], pf);
      unpk4(resR[mt][nf], pr);
      float vf[4], vr[4];
#pragma unroll
      for (int i = 0; i < 4; ++i) {
        vf[i] = pf[i] + elu_f(accF[mt][nf][i]);
        vr[i] = pr[i] + elu_f(accR[mt][nf][i]);
      }
      uint2 of, orv;
      of.x = cvt_pk_bf16(vf[0], vf[1]);
      of.y = cvt_pk_bf16(vf[2], vf[3]);
      orv.x = cvt_pk_bf16(vr[0], vr[1]);
      orv.y = cvt_pk_bf16(vr[2], vr[3]);
      *(uint2*)(sA + off) = of;
      *(uint2*)(sB + off) = orv;
      resF[mt][nf] = of;
      resR[mt][nf] = orv;
    }
  __syncthreads();

  // ---- L3 (sym = f + r -> sA; sym cached in resF) ----
  mfma_dual13(sA, sB, p.W3, p.bs3, accF, accR, wv, lane);
  __syncthreads();
#pragma unroll
  for (int mt = 0; mt < 2; ++mt)
#pragma unroll
    for (int nf = 0; nf < 4; ++nf) {
      int m = mt * 16 + (lane & 15);
      int nb = ((wv << 6) + (nf << 4) + ((lane >> 4) << 2)) << 1;
      int off = swz(m, nb);
      float pf[4], pr[4];
      unpk4(resF[mt][nf], pf);
      unpk4(resR[mt][nf], pr);
      float s[4];
#pragma unroll
      for (int i = 0; i < 4; ++i)
        s[i] = (pf[i] + elu_f(accF[mt][nf][i])) + (pr[i] + elu_f(accR[mt][nf][i]));
      uint2 o;
      o.x = cvt_pk_bf16(s[0], s[1]);
      o.y = cvt_pk_bf16(s[2], s[3]);
      *(uint2*)(sA + off) = o;
      resF[mt][nf] = o;                 // sym (bf16-rounded, same as LDS)
    }
  __syncthreads();

  // ---- heads: t0 (Wt0) and c (Wc0) from sym (sA); t0 cached in resR ----
  mfma_dualW13(sA, p.Wt0, p.Wc0, p.bt0, p.bc0, accF, accR, wv, lane);
  __syncthreads();
#pragma unroll
  for (int mt = 0; mt < 2; ++mt)
#pragma unroll
    for (int nf = 0; nf < 4; ++nf) {
      int m = mt * 16 + (lane & 15);
      int nb = ((wv << 6) + (nf << 4) + ((lane >> 4) << 2)) << 1;
      int off = swz(m, nb);
      float s[4];
      unpk4(resF[mt][nf], s);
      float t0v[4], ccv[4];
#pragma unroll
      for (int i = 0; i < 4; ++i) {
        t0v[i] = s[i] + elu_f(accF[mt][nf][i]);
        ccv[i] = s[i] + elu_f(accR[mt][nf][i]);
      }
      uint2 t0, cc;
      t0.x = cvt_pk_bf16(t0v[0], t0v[1]);
      t0.y = cvt_pk_bf16(t0v[2], t0v[3]);
      cc.x = cvt_pk_bf16(ccv[0], ccv[1]);
      cc.y = cvt_pk_bf16(ccv[2], ccv[3]);
      *(uint2*)(sB + off) = t0;
      *(uint2*)(sA + off) = cc;
      resR[mt][nf] = t0;
    }
  __syncthreads();

  // ---- t1 = t0 + elu(t0@Wt1+bt1), in-place in sB (t0 residual from regs) ----
  mfma_single13(sB, p.Wt1, p.bt1, accF, wv, lane);
  __syncthreads();
#pragma unroll
  for (int mt = 0; mt < 2; ++mt)
#pragma unroll
    for (int nf = 0; nf < 4; ++nf) {
      int m = mt * 16 + (lane & 15);
      int nb = ((wv << 6) + (nf << 4) + ((lane >> 4) << 2)) << 1;
      int off = swz(m, nb);
      float t0[4];
      unpk4(resR[mt][nf], t0);
      float v[4];
#pragma unroll
      for (int i = 0; i < 4; ++i)
        v[i] = t0[i] + elu_f(accF[mt][nf][i]);
      uint2 o;
      o.x = cvt_pk_bf16(v[0], v[1]);
      o.y = cvt_pk_bf16(v[2], v[3]);
      *(uint2*)(sB + off) = o;
    }
  __syncthreads();

  // ---- proj: coeffs from t1 (sB), score from c (sA) ----
  if (tid < BM4 * 12) {
    int row = tid / 12, jj = tid - row * 12;
    int j = (jj < 6) ? jj : jj - 6;
    const char* src = (jj < 6) ? sB : sA;
    const float* W = (jj < 6) ? p.Wt2 : p.Wc1;
    float acc = (jj < 6) ? p.bt2[j] : p.bc1[j];
#pragma unroll 1
    for (int c0 = 0; c0 < 512; c0 += 8) {
      short8 v = *(const short8*)(src + swz(row, c0 * 2));
#pragma unroll
      for (int e = 0; e < 8; ++e) acc += bf2f(v[e]) * W[(c0 + e) * 6 + j];
    }
    sSmall[row * 12 + jj] = acc;
  }
  __syncthreads();
  if (tid < BM4 * 6) {
    int row = tid / 6, j = tid - row * 6;
    int grow = r0 + row;
    if (grow < p.n_tors) {
      float score = sSmall[row * 12 + 6 + j];
      float coeff = sSmall[row * 12 + j];
      p.out[(size_t)grow * 6 + j] = score;
      p.out[(size_t)p.n_tors * 6 + (size_t)grow * 6 + j] =
          coeff * 0.001f * (1.0f / (1.0f + __expf(-score)));
    }
  }
}

// ================= LEGACY PATH (fallback if ws too small) =================

struct Params {
  const float* h;
  const int* idxs;
  const short *W0f, *W0r, *W1, *W2, *W3, *Wt0, *Wt1, *Wc0;
  const float *bs0, *bs1, *bs2, *bs3, *bt0, *bt1, *bt2, *bc0, *bc1;
  const float *Wt2, *Wc1;
  float* out;
  int n_tors;
};

__device__ __forceinline__ void layer_dual(char* hf, char* hr,
                                           const short* __restrict__ W,
                                           const float* __restrict__ bias,
                                           int wv, int lane) {
  f32x4 accf[4][4], accr[4][4];
  const f32x4 z = {0.f, 0.f, 0.f, 0.f};
#pragma unroll
  for (int rt = 0; rt < 4; ++rt)
#pragma unroll
    for (int cf = 0; cf < 4; ++cf) { accf[rt][cf] = z; accr[rt][cf] = z; }
  for (int kt = 0; kt < 16; ++kt) {
    short8 af[4], ar[4], b[4];
#pragma unroll
    for (int rt = 0; rt < 4; ++rt) {
      af[rt] = lds_afrag64(hf, 1024, rt, kt, lane);
      ar[rt] = lds_afrag64(hr, 1024, rt, kt, lane);
    }
#pragma unroll
    for (int cf = 0; cf < 4; ++cf) b[cf] = ldg_bfrag(W, 16, (wv << 2) + cf, kt, lane);
#pragma unroll
    for (int rt = 0; rt < 4; ++rt)
#pragma unroll
      for (int cf = 0; cf < 4; ++cf) {
        accf[rt][cf] = __builtin_amdgcn_mfma_f32_16x16x32_bf16(af[rt], b[cf], accf[rt][cf], 0, 0, 0);
        accr[rt][cf] = __builtin_amdgcn_mfma_f32_16x16x32_bf16(ar[rt], b[cf], accr[rt][cf], 0, 0, 0);
      }
  }
  float bcol[4];
#pragma unroll
  for (int cf = 0; cf < 4; ++cf) bcol[cf] = bias[(wv << 6) + (cf << 4) + (lane & 15)];
  __syncthreads();
#pragma unroll
  for (int rt = 0; rt < 4; ++rt)
#pragma unroll
    for (int cf = 0; cf < 4; ++cf) {
      int col = (wv << 6) + (cf << 4) + (lane & 15);
#pragma unroll
      for (int i = 0; i < 4; ++i) {
        int row = rt * 16 + ((lane >> 4) << 2) + i;
        size_t off = (size_t)row * 1024 + ((col * 2) ^ ((row & 7) << 4));
        short* pf = (short*)(hf + off);
        short* pr = (short*)(hr + off);
        *pf = f2bf(bf2f(*pf) + elu_f(accf[rt][cf][i] + bcol[cf]));
        *pr = f2bf(bf2f(*pr) + elu_f(accr[rt][cf][i] + bcol[cf]));
      }
    }
  __syncthreads();
}

__device__ __forceinline__ void layer_single(const char* in,
                                             const short* __restrict__ W,
                                             const float* __restrict__ bias,
                                             const char* res, char* out,
                                             int wv, int lane) {
  f32x4 acc[4][4];
  const f32x4 z = {0.f, 0.f, 0.f, 0.f};
#pragma unroll
  for (int rt = 0; rt < 4; ++rt)
#pragma unroll
    for (int cf = 0; cf < 4; ++cf) acc[rt][cf] = z;
  for (int kt = 0; kt < 16; ++kt) {
    short8 a[4], b[4];
#pragma unroll
    for (int rt = 0; rt < 4; ++rt) a[rt] = lds_afrag64(in, 1024, rt, kt, lane);
#pragma unroll
    for (int cf = 0; cf < 4; ++cf) b[cf] = ldg_bfrag(W, 16, (wv << 2) + cf, kt, lane);
#pragma unroll
    for (int rt = 0; rt < 4; ++rt)
#pragma unroll
      for (int cf = 0; cf < 4; ++cf)
        acc[rt][cf] = __builtin_amdgcn_mfma_f32_16x16x32_bf16(a[rt], b[cf], acc[rt][cf], 0, 0, 0);
  }
  float bcol[4];
#pragma unroll
  for (int cf = 0; cf < 4; ++cf) bcol[cf] = bias[(wv << 6) + (cf << 4) + (lane & 15)];
  __syncthreads();
#pragma unroll
  for (int rt = 0; rt < 4; ++rt)
#pragma unroll
    for (int cf = 0; cf < 4; ++cf) {
      int col = (wv << 6) + (cf << 4) + (lane & 15);
#pragma unroll
      for (int i = 0; i < 4; ++i) {
        int row = rt * 16 + ((lane >> 4) << 2) + i;
        size_t off = (size_t)row * 1024 + ((col * 2) ^ ((row & 7) << 4));
        float v = elu_f(acc[rt][cf][i] + bcol[cf]) + bf2f(*(const short*)(res + off));
        *(short*)(out + off) = f2bf(v);
      }
    }
  __syncthreads();
}

__global__ __launch_bounds__(NTHREADS) void fused(Params p) {
  __shared__ char smem[BM * 2048];
  __shared__ float sSmall[BM * 12];
  char* sA = smem;
  char* sB = smem + BM * 1024;
  const int tid = threadIdx.x;
  const int lane = tid & 63;
  const int wv = tid >> 6;
  const int r0 = blockIdx.x * BM;

  for (int c = tid; c < BM * 128; c += NTHREADS) {
    int row = c >> 7;
    int col0 = (c & 127) << 3;
    int grow = r0 + row;
    short8 o;
    if (grow < p.n_tors) {
      int f = col0 >> 8;
      int cin = col0 & 255;
      int a = p.idxs[(size_t)grow * 4 + f];
      const float4* s4 = (const float4*)(p.h + (size_t)a * 256 + cin);
      float4 v0 = s4[0], v1 = s4[1];
      o[0] = f2bf(v0.x); o[1] = f2bf(v0.y); o[2] = f2bf(v0.z); o[3] = f2bf(v0.w);
      o[4] = f2bf(v1.x); o[5] = f2bf(v1.y); o[6] = f2bf(v1.z); o[7] = f2bf(v1.w);
    } else {
#pragma unroll
      for (int e = 0; e < 8; ++e) o[e] = 0;
    }
    *(short8*)(smem + (size_t)row * 2048 + ((col0 * 2) ^ ((row & 7) << 4))) = o;
  }
  __syncthreads();

  {
    f32x4 accf[4][4], accr[4][4];
    const f32x4 z = {0.f, 0.f, 0.f, 0.f};
#pragma unroll
    for (int rt = 0; rt < 4; ++rt)
#pragma unroll
      for (int cf = 0; cf < 4; ++cf) { accf[rt][cf] = z; accr[rt][cf] = z; }
    for (int kt = 0; kt < 32; ++kt) {
      short8 a[4], bfw[4], brw[4];
#pragma unroll
      for (int rt = 0; rt < 4; ++rt) a[rt] = lds_afrag64(smem, 2048, rt, kt, lane);
#pragma unroll
      for (int cf = 0; cf < 4; ++cf) {
        bfw[cf] = ldg_bfrag(p.W0f, 32, (wv << 2) + cf, kt, lane);
        brw[cf] = ldg_bfrag(p.W0r, 32, (wv << 2) + cf, kt, lane);
      }
#pragma unroll
      for (int rt = 0; rt < 4; ++rt)
#pragma unroll
        for (int cf = 0; cf < 4; ++cf) {
          accf[rt][cf] = __builtin_amdgcn_mfma_f32_16x16x32_bf16(a[rt], bfw[cf], accf[rt][cf], 0, 0, 0);
          accr[rt][cf] = __builtin_amdgcn_mfma_f32_16x16x32_bf16(a[rt], brw[cf], accr[rt][cf], 0, 0, 0);
        }
    }
    float bcol[4];
#pragma unroll
    for (int cf = 0; cf < 4; ++cf) bcol[cf] = p.bs0[(wv << 6) + (cf << 4) + (lane & 15)];
    __syncthreads();
#pragma unroll
    for (int rt = 0; rt < 4; ++rt)
#pragma unroll
      for (int cf = 0; cf < 4; ++cf) {
        int col = (wv << 6) + (cf << 4) + (lane & 15);
#pragma unroll
        for (int i = 0; i < 4; ++i) {
          int row = rt * 16 + ((lane >> 4) << 2) + i;
          size_t off = (size_t)row * 1024 + ((col * 2) ^ ((row & 7) << 4));
          *(short*)(sA + off) = f2bf(elu_f(accf[rt][cf][i] + bcol[cf]));
          *(short*)(sB + off) = f2bf(elu_f(accr[rt][cf][i] + bcol[cf]));
        }
      }
    __syncthreads();
  }

  layer_dual(sA, sB, p.W1, p.bs1, wv, lane);
  layer_dual(sA, sB, p.W2, p.bs2, wv, lane);
  layer_dual(sA, sB, p.W3, p.bs3, wv, lane);

  for (int c = tid; c < BM * 64; c += NTHREADS) {
    int row = c >> 6;
    int col0 = (c & 63) << 3;
    size_t off = (size_t)row * 1024 + ((col0 * 2) ^ ((row & 7) << 4));
    short8 xa = *(short8*)(sA + off);
    short8 xb = *(short8*)(sB + off);
    short8 o;
#pragma unroll
    for (int e = 0; e < 8; ++e) o[e] = f2bf(bf2f(xa[e]) + bf2f(xb[e]));
    *(short8*)(sA + off) = o;
  }
  __syncthreads();

  layer_single(sA, p.Wt0, p.bt0, sA, sB, wv, lane);
  layer_single(sB, p.Wt1, p.bt1, sB, sB, wv, lane);
  layer_single(sA, p.Wc0, p.bc0, sA, sA, wv, lane);

  for (int idx = tid; idx < BM * 12; idx += NTHREADS) {
    int row = idx / 12, jj = idx - row * 12;
    int j = (jj < 6) ? jj : jj - 6;
    const char* src = (jj < 6) ? sB : sA;
    const float* W = (jj < 6) ? p.Wt2 : p.Wc1;
    float acc = (jj < 6) ? p.bt2[j] : p.bc1[j];
    for (int c0 = 0; c0 < 512; c0 += 8) {
      short8 v = *(const short8*)(src + (size_t)row * 1024 + ((c0 * 2) ^ ((row & 7) << 4)));
#pragma unroll
      for (int e = 0; e < 8; ++e) acc += bf2f(v[e]) * W[(c0 + e) * 6 + j];
    }
    sSmall[row * 12 + jj] = acc;
  }
  __syncthreads();
  for (int idx = tid; idx < BM * 6; idx += NTHREADS) {
    int row = idx / 6, j = idx - row * 6;
    int grow = r0 + row;
    if (grow < p.n_tors) {
      float score = sSmall[row * 12 + 6 + j];
      float coeff = sSmall[row * 12 + j];
      p.out[(size_t)grow * 6 + j] = score;
      p.out[(size_t)p.n_tors * 6 + (size_t)grow * 6 + j] =
          coeff * 0.001f * (1.0f / (1.0f + __expf(-score)));
    }
  }
}

// ================= LAUNCH =================

extern "C" void kernel_launch(void* const* d_in, const int* in_sizes, int n_in,
                              void* d_out, int out_size, void* d_ws, size_t ws_size,
                              hipStream_t stream) {
  const float* h   = (const float*)d_in[0];
  const int* idxs  = (const int*)d_in[1];
  const float* Ws0 = (const float*)d_in[2];
  const float* bs0 = (const float*)d_in[3];
  const float* Ws1 = (const float*)d_in[4];
  const float* bs1 = (const float*)d_in[5];
  const float* Ws2 = (const float*)d_in[6];
  const float* bs2 = (const float*)d_in[7];
  const float* Ws3 = (const float*)d_in[8];
  const float* bs3 = (const float*)d_in[9];
  const float* Wt0 = (const float*)d_in[10];
  const float* bt0 = (const float*)d_in[11];
  const float* Wt1 = (const float*)d_in[12];
  const float* bt1 = (const float*)d_in[13];
  const float* Wt2 = (const float*)d_in[14];
  const float* bt2 = (const float*)d_in[15];
  const float* Wc0 = (const float*)d_in[16];
  const float* bc0 = (const float*)d_in[17];
  const float* Wc1 = (const float*)d_in[18];
  const float* bc1 = (const float*)d_in[19];
  int n_tors = in_sizes[1] / 4;
  int n_atoms = in_sizes[0] / 256;

  auto pk = [&](const float* s, short* dmem, int K, int N, int rev) {
    int tiles = (N >> 4) * (K >> 5);
    pack_w<<<dim3((tiles + 3) / 4), dim3(256), 0, stream>>>(s, dmem, K, N, rev);
  };

  size_t pElems = (size_t)n_atoms * 4 * 512;
  size_t needNew = (pElems + 524288 + 6 * 262144) * sizeof(short);

  if (ws_size >= needNew) {
    short* ws = (short*)d_ws;
    short* pT  = ws;
    short* W0f = ws + pElems;
    short* W1  = W0f + 524288;
    short* W2  = W1 + 262144;
    short* W3  = W2 + 262144;
    short* Wt0c = W3 + 262144;
    short* Wt1c = Wt0c + 262144;
    short* Wc0c = Wt1c + 262144;

    pk(Ws0, W0f, 1024, 512, 0);
    pk(Ws1, W1, 512, 512, 0);
    pk(Ws2, W2, 512, 512, 0);
    pk(Ws3, W3, 512, 512, 0);
    pk(Wt0, Wt0c, 512, 512, 0);
    pk(Wt1, Wt1c, 512, 512, 0);
    pk(Wc0, Wc0c, 512, 512, 0);

    atom_pre<<<dim3((n_atoms + BM - 1) / BM), dim3(NTHREADS), 0, stream>>>(h, W0f, pT, n_atoms);

    P2 p;
    p.idxs = idxs; p.p = pT;
    p.W1 = W1; p.W2 = W2; p.W3 = W3;
    p.Wt0 = Wt0c; p.Wt1 = Wt1c; p.Wc0 = Wc0c;
    p.bs0 = bs0; p.bs1 = bs1; p.bs2 = bs2; p.bs3 = bs3;
    p.bt0 = bt0; p.bt1 = bt1; p.bt2 = bt2; p.bc0 = bc0; p.bc1 = bc1;
    p.Wt2 = Wt2; p.Wc1 = Wc1;
    p.out = (float*)d_out; p.n_tors = n_tors;

    fused13<<<dim3((n_tors + BM4 - 1) / BM4), dim3(NT8), 0, stream>>>(p);
  } else {
    short* ws = (short*)d_ws;
    short* W0f = ws;
    short* W0r = ws + 524288;
    short* W1  = ws + 1048576;
    short* W2  = W1 + 262144;
    short* W3  = W2 + 262144;
    short* Wt0c = W3 + 262144;
    short* Wt1c = Wt0c + 262144;
    short* Wc0c = Wt1c + 262144;

    pk(Ws0, W0f, 1024, 512, 0);
    pk(Ws0, W0r, 1024, 512, 1);
    pk(Ws1, W1, 512, 512, 0);
    pk(Ws2, W2, 512, 512, 0);
    pk(Ws3, W3, 512, 512, 0);
    pk(Wt0, Wt0c, 512, 512, 0);
    pk(Wt1, Wt1c, 512, 512, 0);
    pk(Wc0, Wc0c, 512, 512, 0);

    Params p;
    p.h = h; p.idxs = idxs;
    p.W0f = W0f; p.W0r = W0r; p.W1 = W1; p.W2 = W2; p.W3 = W3;
    p.Wt0 = Wt0c; p.Wt1 = Wt1c; p.Wc0 = Wc0c;
    p.bs0 = bs0; p.bs1 = bs1; p.bs2 = bs2; p.bs3 = bs3;
    p.bt0 = bt0; p.bt1 = bt1; p.bt2 = bt2; p.bc0 = bc0; p.bc1 = bc1;
    p.Wt2 = Wt2; p.Wc1 = Wc1;
    p.out = (float*)d_out; p.n_tors = n_tors;

    fused<<<dim3((n_tors + BM - 1) / BM), dim3(NTHREADS), 0, stream>>>(p);
  }
}

// Round 15
// 2741.353 us; speedup vs baseline: 2.3822x; 1.0792x over previous
//
#include <hip/hip_runtime.h>

#define BM 64
#define NTHREADS 512   // atom_pre / legacy
#define BM4 32
#define NT8 512        // fused11: 8 waves, 2 blocks/CU

typedef __attribute__((ext_vector_type(8))) short short8;
typedef __attribute__((ext_vector_type(4))) short short4v;
typedef __attribute__((ext_vector_type(4))) float f32x4;

__device__ __forceinline__ short f2bf(float f) {
  unsigned u = __builtin_bit_cast(unsigned, f);
  u += 0x7FFFu + ((u >> 16) & 1u);   // RNE
  return (short)(u >> 16);
}
__device__ __forceinline__ float bf2f(short s) {
  unsigned u = ((unsigned)(unsigned short)s) << 16;
  return __builtin_bit_cast(float, u);
}
__device__ __forceinline__ float elu_f(float v) {
  return v > 0.f ? v : (__expf(v) - 1.f);
}
// packed RNE f32x2 -> bf16x2
__device__ __forceinline__ unsigned cvt_pk_bf16(float lo, float hi) {
  unsigned r;
  asm("v_cvt_pk_bf16_f32 %0, %1, %2" : "=v"(r) : "v"(lo), "v"(hi));
  return r;
}

// ---- pack f32 [K][N] weight into 16x16x32 MFMA fragment order ----
__global__ __launch_bounds__(256) void pack_w(const float* __restrict__ src,
                                              short* __restrict__ dst,
                                              int K, int N, int rev) {
  int tile = blockIdx.x * 4 + (threadIdx.x >> 6);
  int lane = threadIdx.x & 63;
  int ktiles = K >> 5;
  int tot = (N >> 4) * ktiles;
  if (tile >= tot) return;
  int nt = tile / ktiles, kt = tile - nt * ktiles;
  int col = (nt << 4) + (lane & 15);
  int k0 = (kt << 5) + ((lane >> 4) << 3);
  short8 o;
#pragma unroll
  for (int j = 0; j < 8; ++j) {
    int kr = k0 + j;
    if (rev) kr = ((3 - (kr >> 8)) << 8) | (kr & 255);
    o[j] = f2bf(src[(size_t)kr * N + col]);
  }
  *(short8*)(dst + (size_t)tile * 512 + lane * 8) = o;
}

__device__ __forceinline__ short8 ldg_bfrag(const short* W, int ktiles, int ct,
                                            int kt, int lane) {
  return *(const short8*)(W + ((size_t)(ct * ktiles + kt) << 9) + (lane << 3));
}

// swizzled LDS byte offset for activation tiles: stride 1024 B/row
__device__ __forceinline__ int swz(int row, int boff) {
  return row * 1024 + (boff ^ ((row & 7) << 4) ^ (((row >> 3) & 1) << 7));
}
// activation fragment read (MFMA B-operand): lane holds row m = mt*16+(lane&15),
// k = kt*32 + (lane>>4)*8 + j
__device__ __forceinline__ short8 lds_act(const char* base, int mt, int kt, int lane) {
  int row = mt * 16 + (lane & 15);
  int boff = (kt << 6) + ((lane >> 4) << 4);
  return *(const short8*)(base + swz(row, boff));
}

// ================= atom precompute (unchanged) =================
__device__ __forceinline__ short8 lds_afrag64(const char* base, int stride, int rt,
                                              int kt, int lane) {
  int row = rt * 16 + (lane & 15);
  int boff = (kt << 6) + ((lane >> 4) << 4);
  return *(const short8*)(base + row * stride + (boff ^ ((row & 7) << 4)));
}

__global__ __launch_bounds__(NTHREADS) void atom_pre(const float* __restrict__ h,
                                                     const short* __restrict__ W0f,
                                                     short* __restrict__ p,
                                                     int n_atoms) {
  __shared__ char sh[BM * 512];
  const int tid = threadIdx.x, lane = tid & 63, wv = tid >> 6;
  const int r0 = blockIdx.x * BM;
  for (int i = tid; i < BM * 32; i += NTHREADS) {
    int row = i >> 5, c0 = (i & 31) << 3;
    int ga = r0 + row;
    short8 o;
    if (ga < n_atoms) {
      const float4* s4 = (const float4*)(h + (size_t)ga * 256 + c0);
      float4 v0 = s4[0], v1 = s4[1];
      o[0] = f2bf(v0.x); o[1] = f2bf(v0.y); o[2] = f2bf(v0.z); o[3] = f2bf(v0.w);
      o[4] = f2bf(v1.x); o[5] = f2bf(v1.y); o[6] = f2bf(v1.z); o[7] = f2bf(v1.w);
    } else {
#pragma unroll
      for (int e = 0; e < 8; ++e) o[e] = 0;
    }
    *(short8*)(sh + row * 512 + ((c0 * 2) ^ ((row & 7) << 4))) = o;
  }
  __syncthreads();
#pragma unroll 1
  for (int s = 0; s < 4; ++s) {
    f32x4 acc[4][4];
    const f32x4 z = {0.f, 0.f, 0.f, 0.f};
#pragma unroll
    for (int rt = 0; rt < 4; ++rt)
#pragma unroll
      for (int cf = 0; cf < 4; ++cf) acc[rt][cf] = z;
    for (int kt = 0; kt < 8; ++kt) {
      short8 a[4], b[4];
#pragma unroll
      for (int rt = 0; rt < 4; ++rt) a[rt] = lds_afrag64(sh, 512, rt, kt, lane);
#pragma unroll
      for (int cf = 0; cf < 4; ++cf)
        b[cf] = ldg_bfrag(W0f, 32, (wv << 2) + cf, (s << 3) + kt, lane);
#pragma unroll
      for (int rt = 0; rt < 4; ++rt)
#pragma unroll
        for (int cf = 0; cf < 4; ++cf)
          acc[rt][cf] = __builtin_amdgcn_mfma_f32_16x16x32_bf16(a[rt], b[cf], acc[rt][cf], 0, 0, 0);
    }
#pragma unroll
    for (int rt = 0; rt < 4; ++rt)
#pragma unroll
      for (int cf = 0; cf < 4; ++cf) {
        int col = (wv << 6) + (cf << 4) + (lane & 15);
#pragma unroll
        for (int i = 0; i < 4; ++i) {
          int row = rt * 16 + ((lane >> 4) << 2) + i;
          int ga = r0 + row;
          if (ga < n_atoms) p[((size_t)ga * 4 + s) * 512 + col] = f2bf(acc[rt][cf][i]);
        }
      }
  }
}

struct P2 {
  const int* idxs;
  const short* p;
  const short *W1, *W2, *W3, *Wt0, *Wt1, *Wc0;
  const float *bs0, *bs1, *bs2, *bs3, *bt0, *bt1, *bt2, *bc0, *bc1;
  const float *Wt2, *Wc1;
  float* out;
  int n_tors;
};

// ================= fused11: transposed compute + setprio (best verified) =======
// Transposed compute Y^T = W^T . X^T. Weight packed frag = A-operand; activation
// LDS read = B-operand. D: lane holds m = mt*16+(lane&15), n0..n0+3 consecutive.

__device__ __forceinline__ void bias_init(const float* __restrict__ bias,
                                          f32x4 (&acc)[2][4], int wv, int lane) {
#pragma unroll
  for (int nf = 0; nf < 4; ++nf) {
    const float4 bv = *(const float4*)(bias + (wv << 6) + (nf << 4) + ((lane >> 4) << 2));
    f32x4 v = {bv.x, bv.y, bv.z, bv.w};
    acc[0][nf] = v;
    acc[1][nf] = v;
  }
}

// dual-chain MFMA (shared weight-A): aF = bias + X_A@W, aR = bias + X_B@W
__device__ __forceinline__ void mfma_dual11(const char* sA, const char* sB,
                                            const short* __restrict__ W,
                                            const float* __restrict__ bias,
                                            f32x4 (&aF)[2][4], f32x4 (&aR)[2][4],
                                            int wv, int lane) {
  bias_init(bias, aF, wv, lane);
  bias_init(bias, aR, wv, lane);
#pragma unroll 4
  for (int kt = 0; kt < 16; ++kt) {
    short8 w[4];
#pragma unroll
    for (int nf = 0; nf < 4; ++nf) w[nf] = ldg_bfrag(W, 16, (wv << 2) + nf, kt, lane);
    short8 bf_[2], br_[2];
#pragma unroll
    for (int mt = 0; mt < 2; ++mt) {
      bf_[mt] = lds_act(sA, mt, kt, lane);
      br_[mt] = lds_act(sB, mt, kt, lane);
    }
    __builtin_amdgcn_s_setprio(1);
#pragma unroll
    for (int mt = 0; mt < 2; ++mt)
#pragma unroll
      for (int nf = 0; nf < 4; ++nf) {
        aF[mt][nf] = __builtin_amdgcn_mfma_f32_16x16x32_bf16(w[nf], bf_[mt], aF[mt][nf], 0, 0, 0);
        aR[mt][nf] = __builtin_amdgcn_mfma_f32_16x16x32_bf16(w[nf], br_[mt], aR[mt][nf], 0, 0, 0);
      }
    __builtin_amdgcn_s_setprio(0);
  }
}

// dual-weight MFMA: one activation stream (sym), two weight streams
__device__ __forceinline__ void mfma_dualW11(const char* sA,
                                             const short* __restrict__ Wa,
                                             const short* __restrict__ Wb,
                                             const float* __restrict__ ba,
                                             const float* __restrict__ bb,
                                             f32x4 (&aA)[2][4], f32x4 (&aB)[2][4],
                                             int wv, int lane) {
  bias_init(ba, aA, wv, lane);
  bias_init(bb, aB, wv, lane);
#pragma unroll 4
  for (int kt = 0; kt < 16; ++kt) {
    short8 wA[4], wB[4];
#pragma unroll
    for (int nf = 0; nf < 4; ++nf) {
      wA[nf] = ldg_bfrag(Wa, 16, (wv << 2) + nf, kt, lane);
      wB[nf] = ldg_bfrag(Wb, 16, (wv << 2) + nf, kt, lane);
    }
    short8 b[2];
#pragma unroll
    for (int mt = 0; mt < 2; ++mt) b[mt] = lds_act(sA, mt, kt, lane);
    __builtin_amdgcn_s_setprio(1);
#pragma unroll
    for (int mt = 0; mt < 2; ++mt)
#pragma unroll
      for (int nf = 0; nf < 4; ++nf) {
        aA[mt][nf] = __builtin_amdgcn_mfma_f32_16x16x32_bf16(wA[nf], b[mt], aA[mt][nf], 0, 0, 0);
        aB[mt][nf] = __builtin_amdgcn_mfma_f32_16x16x32_bf16(wB[nf], b[mt], aB[mt][nf], 0, 0, 0);
      }
    __builtin_amdgcn_s_setprio(0);
  }
}

// single-chain MFMA
__device__ __forceinline__ void mfma_single11(const char* src,
                                              const short* __restrict__ W,
                                              const float* __restrict__ bias,
                                              f32x4 (&acc)[2][4], int wv, int lane) {
  bias_init(bias, acc, wv, lane);
#pragma unroll 4
  for (int kt = 0; kt < 16; ++kt) {
    short8 w[4];
#pragma unroll
    for (int nf = 0; nf < 4; ++nf) w[nf] = ldg_bfrag(W, 16, (wv << 2) + nf, kt, lane);
    short8 b[2];
#pragma unroll
    for (int mt = 0; mt < 2; ++mt) b[mt] = lds_act(src, mt, kt, lane);
    __builtin_amdgcn_s_setprio(1);
#pragma unroll
    for (int mt = 0; mt < 2; ++mt)
#pragma unroll
      for (int nf = 0; nf < 4; ++nf)
        acc[mt][nf] = __builtin_amdgcn_mfma_f32_16x16x32_bf16(w[nf], b[mt], acc[mt][nf], 0, 0, 0);
    __builtin_amdgcn_s_setprio(0);
  }
}

__global__ __launch_bounds__(NT8, 4) void fused11(P2 p) {
  __shared__ char sA[BM4 * 1024];      // 32 KB, row-major [m][n] + XOR swizzle
  __shared__ char sB[BM4 * 1024];      // 32 KB
  __shared__ int sIdx[BM4 * 4];
  __shared__ float sSmall[BM4 * 12];
  const int tid = threadIdx.x;
  const int lane = tid & 63;
  const int wv = tid >> 6;             // 0..7 ; wave owns out-features wv*64..wv*64+63
  const int r0 = blockIdx.x * BM4;

  if (tid < BM4 * 4) {
    int grow = r0 + (tid >> 2);
    sIdx[tid] = (grow < p.n_tors) ? p.idxs[(size_t)grow * 4 + (tid & 3)] : 0;
  }
  __syncthreads();

  // ---- G: layer0 via gathered per-atom partials -> sA (fwd), sB (rev) ----
#pragma unroll 1
  for (int i = tid; i < BM4 * 64; i += NT8) {
    int row = i >> 6, c0 = (i & 63) << 3;
    float sf[8], sr[8];
#pragma unroll
    for (int e = 0; e < 8; ++e) { sf[e] = p.bs0[c0 + e]; sr[e] = sf[e]; }
#pragma unroll
    for (int j = 0; j < 4; ++j) {
      int a = sIdx[row * 4 + j];
      short8 vf = *(const short8*)(p.p + ((size_t)a * 4 + j) * 512 + c0);
      short8 vr = *(const short8*)(p.p + ((size_t)a * 4 + (3 - j)) * 512 + c0);
#pragma unroll
      for (int e = 0; e < 8; ++e) { sf[e] += bf2f(vf[e]); sr[e] += bf2f(vr[e]); }
    }
    uint4 of, orv;
    of.x = cvt_pk_bf16(elu_f(sf[0]), elu_f(sf[1]));
    of.y = cvt_pk_bf16(elu_f(sf[2]), elu_f(sf[3]));
    of.z = cvt_pk_bf16(elu_f(sf[4]), elu_f(sf[5]));
    of.w = cvt_pk_bf16(elu_f(sf[6]), elu_f(sf[7]));
    orv.x = cvt_pk_bf16(elu_f(sr[0]), elu_f(sr[1]));
    orv.y = cvt_pk_bf16(elu_f(sr[2]), elu_f(sr[3]));
    orv.z = cvt_pk_bf16(elu_f(sr[4]), elu_f(sr[5]));
    orv.w = cvt_pk_bf16(elu_f(sr[6]), elu_f(sr[7]));
    int off = swz(row, c0 * 2);
    *(uint4*)(sA + off) = of;
    *(uint4*)(sB + off) = orv;
  }
  __syncthreads();

  f32x4 accF[2][4], accR[2][4];

  // ---- 3 dual residual layers (shared weight-A), in-place; last writes sym->sA --
  const short* Ws[3] = {p.W1, p.W2, p.W3};
  const float* bs[3] = {p.bs1, p.bs2, p.bs3};
#pragma unroll 1
  for (int L = 0; L < 3; ++L) {
    mfma_dual11(sA, sB, Ws[L], bs[L], accF, accR, wv, lane);
    __syncthreads();
#pragma unroll
    for (int mt = 0; mt < 2; ++mt)
#pragma unroll
      for (int nf = 0; nf < 4; ++nf) {
        int m = mt * 16 + (lane & 15);
        int nb = ((wv << 6) + (nf << 4) + ((lane >> 4) << 2)) << 1;
        int off = swz(m, nb);
        short4v rf = *(short4v*)(sA + off);
        short4v rr = *(short4v*)(sB + off);
        float vf[4], vr[4];
#pragma unroll
        for (int i = 0; i < 4; ++i) {
          vf[i] = bf2f(rf[i]) + elu_f(accF[mt][nf][i]);
          vr[i] = bf2f(rr[i]) + elu_f(accR[mt][nf][i]);
        }
        if (L == 2) {
          uint2 o;
          o.x = cvt_pk_bf16(vf[0] + vr[0], vf[1] + vr[1]);
          o.y = cvt_pk_bf16(vf[2] + vr[2], vf[3] + vr[3]);
          *(uint2*)(sA + off) = o;
        } else {
          uint2 of, orv;
          of.x = cvt_pk_bf16(vf[0], vf[1]);
          of.y = cvt_pk_bf16(vf[2], vf[3]);
          orv.x = cvt_pk_bf16(vr[0], vr[1]);
          orv.y = cvt_pk_bf16(vr[2], vr[3]);
          *(uint2*)(sA + off) = of;
          *(uint2*)(sB + off) = orv;
        }
      }
    __syncthreads();
  }

  // ---- heads: t0 (Wt0) and c (Wc0) from sym (sA), one activation stream ----
  mfma_dualW11(sA, p.Wt0, p.Wc0, p.bt0, p.bc0, accF, accR, wv, lane);
  __syncthreads();
#pragma unroll
  for (int mt = 0; mt < 2; ++mt)
#pragma unroll
    for (int nf = 0; nf < 4; ++nf) {
      int m = mt * 16 + (lane & 15);
      int nb = ((wv << 6) + (nf << 4) + ((lane >> 4) << 2)) << 1;
      int off = swz(m, nb);
      short4v sres = *(short4v*)(sA + off);
      float t0v[4], ccv[4];
#pragma unroll
      for (int i = 0; i < 4; ++i) {
        float s = bf2f(sres[i]);
        t0v[i] = s + elu_f(accF[mt][nf][i]);
        ccv[i] = s + elu_f(accR[mt][nf][i]);
      }
      uint2 t0, cc;
      t0.x = cvt_pk_bf16(t0v[0], t0v[1]);
      t0.y = cvt_pk_bf16(t0v[2], t0v[3]);
      cc.x = cvt_pk_bf16(ccv[0], ccv[1]);
      cc.y = cvt_pk_bf16(ccv[2], ccv[3]);
      *(uint2*)(sB + off) = t0;
      *(uint2*)(sA + off) = cc;
    }
  __syncthreads();

  // ---- t1 = t0 + elu(t0@Wt1+bt1), in-place in sB ----
  mfma_single11(sB, p.Wt1, p.bt1, accF, wv, lane);
  __syncthreads();
#pragma unroll
  for (int mt = 0; mt < 2; ++mt)
#pragma unroll
    for (int nf = 0; nf < 4; ++nf) {
      int m = mt * 16 + (lane & 15);
      int nb = ((wv << 6) + (nf << 4) + ((lane >> 4) << 2)) << 1;
      int off = swz(m, nb);
      short4v rt_ = *(short4v*)(sB + off);
      float v[4];
#pragma unroll
      for (int i = 0; i < 4; ++i)
        v[i] = bf2f(rt_[i]) + elu_f(accF[mt][nf][i]);
      uint2 o;
      o.x = cvt_pk_bf16(v[0], v[1]);
      o.y = cvt_pk_bf16(v[2], v[3]);
      *(uint2*)(sB + off) = o;
    }
  __syncthreads();

  // ---- proj: coeffs from t1 (sB), score from c (sA) ----
  if (tid < BM4 * 12) {
    int row = tid / 12, jj = tid - row * 12;
    int j = (jj < 6) ? jj : jj - 6;
    const char* src = (jj < 6) ? sB : sA;
    const float* W = (jj < 6) ? p.Wt2 : p.Wc1;
    float acc = (jj < 6) ? p.bt2[j] : p.bc1[j];
#pragma unroll 1
    for (int c0 = 0; c0 < 512; c0 += 8) {
      short8 v = *(const short8*)(src + swz(row, c0 * 2));
#pragma unroll
      for (int e = 0; e < 8; ++e) acc += bf2f(v[e]) * W[(c0 + e) * 6 + j];
    }
    sSmall[row * 12 + jj] = acc;
  }
  __syncthreads();
  if (tid < BM4 * 6) {
    int row = tid / 6, j = tid - row * 6;
    int grow = r0 + row;
    if (grow < p.n_tors) {
      float score = sSmall[row * 12 + 6 + j];
      float coeff = sSmall[row * 12 + j];
      p.out[(size_t)grow * 6 + j] = score;
      p.out[(size_t)p.n_tors * 6 + (size_t)grow * 6 + j] =
          coeff * 0.001f * (1.0f / (1.0f + __expf(-score)));
    }
  }
}

// ================= LEGACY PATH (fallback if ws too small) =================

struct Params {
  const float* h;
  const int* idxs;
  const short *W0f, *W0r, *W1, *W2, *W3, *Wt0, *Wt1, *Wc0;
  const float *bs0, *bs1, *bs2, *bs3, *bt0, *bt1, *bt2, *bc0, *bc1;
  const float *Wt2, *Wc1;
  float* out;
  int n_tors;
};

__device__ __forceinline__ void layer_dual(char* hf, char* hr,
                                           const short* __restrict__ W,
                                           const float* __restrict__ bias,
                                           int wv, int lane) {
  f32x4 accf[4][4], accr[4][4];
  const f32x4 z = {0.f, 0.f, 0.f, 0.f};
#pragma unroll
  for (int rt = 0; rt < 4; ++rt)
#pragma unroll
    for (int cf = 0; cf < 4; ++cf) { accf[rt][cf] = z; accr[rt][cf] = z; }
  for (int kt = 0; kt < 16; ++kt) {
    short8 af[4], ar[4], b[4];
#pragma unroll
    for (int rt = 0; rt < 4; ++rt) {
      af[rt] = lds_afrag64(hf, 1024, rt, kt, lane);
      ar[rt] = lds_afrag64(hr, 1024, rt, kt, lane);
    }
#pragma unroll
    for (int cf = 0; cf < 4; ++cf) b[cf] = ldg_bfrag(W, 16, (wv << 2) + cf, kt, lane);
#pragma unroll
    for (int rt = 0; rt < 4; ++rt)
#pragma unroll
      for (int cf = 0; cf < 4; ++cf) {
        accf[rt][cf] = __builtin_amdgcn_mfma_f32_16x16x32_bf16(af[rt], b[cf], accf[rt][cf], 0, 0, 0);
        accr[rt][cf] = __builtin_amdgcn_mfma_f32_16x16x32_bf16(ar[rt], b[cf], accr[rt][cf], 0, 0, 0);
      }
  }
  float bcol[4];
#pragma unroll
  for (int cf = 0; cf < 4; ++cf) bcol[cf] = bias[(wv << 6) + (cf << 4) + (lane & 15)];
  __syncthreads();
#pragma unroll
  for (int rt = 0; rt < 4; ++rt)
#pragma unroll
    for (int cf = 0; cf < 4; ++cf) {
      int col = (wv << 6) + (cf << 4) + (lane & 15);
#pragma unroll
      for (int i = 0; i < 4; ++i) {
        int row = rt * 16 + ((lane >> 4) << 2) + i;
        size_t off = (size_t)row * 1024 + ((col * 2) ^ ((row & 7) << 4));
        short* pf = (short*)(hf + off);
        short* pr = (short*)(hr + off);
        *pf = f2bf(bf2f(*pf) + elu_f(accf[rt][cf][i] + bcol[cf]));
        *pr = f2bf(bf2f(*pr) + elu_f(accr[rt][cf][i] + bcol[cf]));
      }
    }
  __syncthreads();
}

__device__ __forceinline__ void layer_single(const char* in,
                                             const short* __restrict__ W,
                                             const float* __restrict__ bias,
                                             const char* res, char* out,
                                             int wv, int lane) {
  f32x4 acc[4][4];
  const f32x4 z = {0.f, 0.f, 0.f, 0.f};
#pragma unroll
  for (int rt = 0; rt < 4; ++rt)
#pragma unroll
    for (int cf = 0; cf < 4; ++cf) acc[rt][cf] = z;
  for (int kt = 0; kt < 16; ++kt) {
    short8 a[4], b[4];
#pragma unroll
    for (int rt = 0; rt < 4; ++rt) a[rt] = lds_afrag64(in, 1024, rt, kt, lane);
#pragma unroll
    for (int cf = 0; cf < 4; ++cf) b[cf] = ldg_bfrag(W, 16, (wv << 2) + cf, kt, lane);
#pragma unroll
    for (int rt = 0; rt < 4; ++rt)
#pragma unroll
      for (int cf = 0; cf < 4; ++cf)
        acc[rt][cf] = __builtin_amdgcn_mfma_f32_16x16x32_bf16(a[rt], b[cf], acc[rt][cf], 0, 0, 0);
  }
  float bcol[4];
#pragma unroll
  for (int cf = 0; cf < 4; ++cf) bcol[cf] = bias[(wv << 6) + (cf << 4) + (lane & 15)];
  __syncthreads();
#pragma unroll
  for (int rt = 0; rt < 4; ++rt)
#pragma unroll
    for (int cf = 0; cf < 4; ++cf) {
      int col = (wv << 6) + (cf << 4) + (lane & 15);
#pragma unroll
      for (int i = 0; i < 4; ++i) {
        int row = rt * 16 + ((lane >> 4) << 2) + i;
        size_t off = (size_t)row * 1024 + ((col * 2) ^ ((row & 7) << 4));
        float v = elu_f(acc[rt][cf][i] + bcol[cf]) + bf2f(*(const short*)(res + off));
        *(short*)(out + off) = f2bf(v);
      }
    }
  __syncthreads();
}

__global__ __launch_bounds__(NTHREADS) void fused(Params p) {
  __shared__ char smem[BM * 2048];
  __shared__ float sSmall[BM * 12];
  char* sA = smem;
  char* sB = smem + BM * 1024;
  const int tid = threadIdx.x;
  const int lane = tid & 63;
  const int wv = tid >> 6;
  const int r0 = blockIdx.x * BM;

  for (int c = tid; c < BM * 128; c += NTHREADS) {
    int row = c >> 7;
    int col0 = (c & 127) << 3;
    int grow = r0 + row;
    short8 o;
    if (grow < p.n_tors) {
      int f = col0 >> 8;
      int cin = col0 & 255;
      int a = p.idxs[(size_t)grow * 4 + f];
      const float4* s4 = (const float4*)(p.h + (size_t)a * 256 + cin);
      float4 v0 = s4[0], v1 = s4[1];
      o[0] = f2bf(v0.x); o[1] = f2bf(v0.y); o[2] = f2bf(v0.z); o[3] = f2bf(v0.w);
      o[4] = f2bf(v1.x); o[5] = f2bf(v1.y); o[6] = f2bf(v1.z); o[7] = f2bf(v1.w);
    } else {
#pragma unroll
      for (int e = 0; e < 8; ++e) o[e] = 0;
    }
    *(short8*)(smem + (size_t)row * 2048 + ((col0 * 2) ^ ((row & 7) << 4))) = o;
  }
  __syncthreads();

  {
    f32x4 accf[4][4], accr[4][4];
    const f32x4 z = {0.f, 0.f, 0.f, 0.f};
#pragma unroll
    for (int rt = 0; rt < 4; ++rt)
#pragma unroll
      for (int cf = 0; cf < 4; ++cf) { accf[rt][cf] = z; accr[rt][cf] = z; }
    for (int kt = 0; kt < 32; ++kt) {
      short8 a[4], bfw[4], brw[4];
#pragma unroll
      for (int rt = 0; rt < 4; ++rt) a[rt] = lds_afrag64(smem, 2048, rt, kt, lane);
#pragma unroll
      for (int cf = 0; cf < 4; ++cf) {
        bfw[cf] = ldg_bfrag(p.W0f, 32, (wv << 2) + cf, kt, lane);
        brw[cf] = ldg_bfrag(p.W0r, 32, (wv << 2) + cf, kt, lane);
      }
#pragma unroll
      for (int rt = 0; rt < 4; ++rt)
#pragma unroll
        for (int cf = 0; cf < 4; ++cf) {
          accf[rt][cf] = __builtin_amdgcn_mfma_f32_16x16x32_bf16(a[rt], bfw[cf], accf[rt][cf], 0, 0, 0);
          accr[rt][cf] = __builtin_amdgcn_mfma_f32_16x16x32_bf16(a[rt], brw[cf], accr[rt][cf], 0, 0, 0);
        }
    }
    float bcol[4];
#pragma unroll
    for (int cf = 0; cf < 4; ++cf) bcol[cf] = p.bs0[(wv << 6) + (cf << 4) + (lane & 15)];
    __syncthreads();
#pragma unroll
    for (int rt = 0; rt < 4; ++rt)
#pragma unroll
      for (int cf = 0; cf < 4; ++cf) {
        int col = (wv << 6) + (cf << 4) + (lane & 15);
#pragma unroll
        for (int i = 0; i < 4; ++i) {
          int row = rt * 16 + ((lane >> 4) << 2) + i;
          size_t off = (size_t)row * 1024 + ((col * 2) ^ ((row & 7) << 4));
          *(short*)(sA + off) = f2bf(elu_f(accf[rt][cf][i] + bcol[cf]));
          *(short*)(sB + off) = f2bf(elu_f(accr[rt][cf][i] + bcol[cf]));
        }
      }
    __syncthreads();
  }

  layer_dual(sA, sB, p.W1, p.bs1, wv, lane);
  layer_dual(sA, sB, p.W2, p.bs2, wv, lane);
  layer_dual(sA, sB, p.W3, p.bs3, wv, lane);

  for (int c = tid; c < BM * 64; c += NTHREADS) {
    int row = c >> 6;
    int col0 = (c & 63) << 3;
    size_t off = (size_t)row * 1024 + ((col0 * 2) ^ ((row & 7) << 4));
    short8 xa = *(short8*)(sA + off);
    short8 xb = *(short8*)(sB + off);
    short8 o;
#pragma unroll
    for (int e = 0; e < 8; ++e) o[e] = f2bf(bf2f(xa[e]) + bf2f(xb[e]));
    *(short8*)(sA + off) = o;
  }
  __syncthreads();

  layer_single(sA, p.Wt0, p.bt0, sA, sB, wv, lane);
  layer_single(sB, p.Wt1, p.bt1, sB, sB, wv, lane);
  layer_single(sA, p.Wc0, p.bc0, sA, sA, wv, lane);

  for (int idx = tid; idx < BM * 12; idx += NTHREADS) {
    int row = idx / 12, jj = idx - row * 12;
    int j = (jj < 6) ? jj : jj - 6;
    const char* src = (jj < 6) ? sB : sA;
    const float* W = (jj < 6) ? p.Wt2 : p.Wc1;
    float acc = (jj < 6) ? p.bt2[j] : p.bc1[j];
    for (int c0 = 0; c0 < 512; c0 += 8) {
      short8 v = *(const short8*)(src + (size_t)row * 1024 + ((c0 * 2) ^ ((row & 7) << 4)));
#pragma unroll
      for (int e = 0; e < 8; ++e) acc += bf2f(v[e]) * W[(c0 + e) * 6 + j];
    }
    sSmall[row * 12 + jj] = acc;
  }
  __syncthreads();
  for (int idx = tid; idx < BM * 6; idx += NTHREADS) {
    int row = idx / 6, j = idx - row * 6;
    int grow = r0 + row;
    if (grow < p.n_tors) {
      float score = sSmall[row * 12 + 6 + j];
      float coeff = sSmall[row * 12 + j];
      p.out[(size_t)grow * 6 + j] = score;
      p.out[(size_t)p.n_tors * 6 + (size_t)grow * 6 + j] =
          coeff * 0.001f * (1.0f / (1.0f + __expf(-score)));
    }
  }
}

// ================= LAUNCH =================

extern "C" void kernel_launch(void* const* d_in, const int* in_sizes, int n_in,
                              void* d_out, int out_size, void* d_ws, size_t ws_size,
                              hipStream_t stream) {
  const float* h   = (const float*)d_in[0];
  const int* idxs  = (const int*)d_in[1];
  const float* Ws0 = (const float*)d_in[2];
  const float* bs0 = (const float*)d_in[3];
  const float* Ws1 = (const float*)d_in[4];
  const float* bs1 = (const float*)d_in[5];
  const float* Ws2 = (const float*)d_in[6];
  const float* bs2 = (const float*)d_in[7];
  const float* Ws3 = (const float*)d_in[8];
  const float* bs3 = (const float*)d_in[9];
  const float* Wt0 = (const float*)d_in[10];
  const float* bt0 = (const float*)d_in[11];
  const float* Wt1 = (const float*)d_in[12];
  const float* bt1 = (const float*)d_in[13];
  const float* Wt2 = (const float*)d_in[14];
  const float* bt2 = (const float*)d_in[15];
  const float* Wc0 = (const float*)d_in[16];
  const float* bc0 = (const float*)d_in[17];
  const float* Wc1 = (const float*)d_in[18];
  const float* bc1 = (const float*)d_in[19];
  int n_tors = in_sizes[1] / 4;
  int n_atoms = in_sizes[0] / 256;

  auto pk = [&](const float* s, short* dmem, int K, int N, int rev) {
    int tiles = (N >> 4) * (K >> 5);
    pack_w<<<dim3((tiles + 3) / 4), dim3(256), 0, stream>>>(s, dmem, K, N, rev);
  };

  size_t pElems = (size_t)n_atoms * 4 * 512;
  size_t needNew = (pElems + 524288 + 6 * 262144) * sizeof(short);

  if (ws_size >= needNew) {
    short* ws = (short*)d_ws;
    short* pT  = ws;
    short* W0f = ws + pElems;
    short* W1  = W0f + 524288;
    short* W2  = W1 + 262144;
    short* W3  = W2 + 262144;
    short* Wt0c = W3 + 262144;
    short* Wt1c = Wt0c + 262144;
    short* Wc0c = Wt1c + 262144;

    pk(Ws0, W0f, 1024, 512, 0);
    pk(Ws1, W1, 512, 512, 0);
    pk(Ws2, W2, 512, 512, 0);
    pk(Ws3, W3, 512, 512, 0);
    pk(Wt0, Wt0c, 512, 512, 0);
    pk(Wt1, Wt1c, 512, 512, 0);
    pk(Wc0, Wc0c, 512, 512, 0);

    atom_pre<<<dim3((n_atoms + BM - 1) / BM), dim3(NTHREADS), 0, stream>>>(h, W0f, pT, n_atoms);

    P2 p;
    p.idxs = idxs; p.p = pT;
    p.W1 = W1; p.W2 = W2; p.W3 = W3;
    p.Wt0 = Wt0c; p.Wt1 = Wt1c; p.Wc0 = Wc0c;
    p.bs0 = bs0; p.bs1 = bs1; p.bs2 = bs2; p.bs3 = bs3;
    p.bt0 = bt0; p.bt1 = bt1; p.bt2 = bt2; p.bc0 = bc0; p.bc1 = bc1;
    p.Wt2 = Wt2; p.Wc1 = Wc1;
    p.out = (float*)d_out; p.n_tors = n_tors;

    fused11<<<dim3((n_tors + BM4 - 1) / BM4), dim3(NT8), 0, stream>>>(p);
  } else {
    short* ws = (short*)d_ws;
    short* W0f = ws;
    short* W0r = ws + 524288;
    short* W1  = ws + 1048576;
    short* W2  = W1 + 262144;
    short* W3  = W2 + 262144;
    short* Wt0c = W3 + 262144;
    short* Wt1c = Wt0c + 262144;
    short* Wc0c = Wt1c + 262144;

    pk(Ws0, W0f, 1024, 512, 0);
    pk(Ws0, W0r, 1024, 512, 1);
    pk(Ws1, W1, 512, 512, 0);
    pk(Ws2, W2, 512, 512, 0);
    pk(Ws3, W3, 512, 512, 0);
    pk(Wt0, Wt0c, 512, 512, 0);
    pk(Wt1, Wt1c, 512, 512, 0);
    pk(Wc0, Wc0c, 512, 512, 0);

    Params p;
    p.h = h; p.idxs = idxs;
    p.W0f = W0f; p.W0r = W0r; p.W1 = W1; p.W2 = W2; p.W3 = W3;
    p.Wt0 = Wt0c; p.Wt1 = Wt1c; p.Wc0 = Wc0c;
    p.bs0 = bs0; p.bs1 = bs1; p.bs2 = bs2; p.bs3 = bs3;
    p.bt0 = bt0; p.bt1 = bt1; p.bt2 = bt2; p.bc0 = bc0; p.bc1 = bc1;
    p.Wt2 = Wt2; p.Wc1 = Wc1;
    p.out = (float*)d_out; p.n_tors = n_tors;

    fused<<<dim3((n_tors + BM - 1) / BM), dim3(NTHREADS), 0, stream>>>(p);
  }
}